// Round 10
// baseline (820.049 us; speedup 1.0000x reference)
//
#include <hip/hip_runtime.h>
#include <stdint.h>

#define N_NODES 100000
#define N_EDGES 600000
#define HID 128
#define OUT_C 64
#define NELEMS 12800000      // 100000*128
#define BN_EPS 1e-5f

// ---------------- threefry2x32 (matches JAX) ----------------
__device__ __host__ __forceinline__ void threefry2x32(uint32_t k0, uint32_t k1,
                                                      uint32_t x0, uint32_t x1,
                                                      uint32_t& o0, uint32_t& o1) {
  uint32_t ks0 = k0, ks1 = k1, ks2 = k0 ^ k1 ^ 0x1BD11BDAu;
  x0 += ks0; x1 += ks1;
#define TFR(r) { x0 += x1; x1 = (x1 << (r)) | (x1 >> (32 - (r))); x1 ^= x0; }
  TFR(13) TFR(15) TFR(26) TFR(6)
  x0 += ks1; x1 += ks2 + 1u;
  TFR(17) TFR(29) TFR(16) TFR(24)
  x0 += ks2; x1 += ks0 + 2u;
  TFR(13) TFR(15) TFR(26) TFR(6)
  x0 += ks0; x1 += ks1 + 3u;
  TFR(17) TFR(29) TFR(16) TFR(24)
  x0 += ks1; x1 += ks2 + 4u;
  TFR(13) TFR(15) TFR(26) TFR(6)
  x0 += ks2; x1 += ks0 + 5u;
#undef TFR
  o0 = x0; o1 = x1;
}

// JAX threefry_partitionable random_bits for flat index i: out0^out1 of threefry(key,(0,i))
__device__ __forceinline__ uint32_t jax_bits32(uint32_t k0, uint32_t k1, uint32_t i) {
  uint32_t b0, b1;
  threefry2x32(k0, k1, 0u, i, b0, b1);
  return b0 ^ b1;
}

// ---------------- plain GEMM (layer 1): O[r][c] = sum_k A[r][k]*W[k][c]
__global__ __launch_bounds__(256) void gemm_nk128(const float* __restrict__ A,
                                                  const float* __restrict__ W,
                                                  float* __restrict__ O) {
  __shared__ __align__(16) float Wl[64 * 128];
  __shared__ __align__(16) float At[64 * 36];
  const int tid = threadIdx.x;
  const int lane = tid & 63;
  const int wv = tid >> 6;
  const int rbase = blockIdx.x * 32;
  const int r0 = wv * 8;

  float acc0[8], acc1[8];
#pragma unroll
  for (int i = 0; i < 8; ++i) { acc0[i] = 0.f; acc1[i] = 0.f; }

  for (int kh = 0; kh < 2; ++kh) {
    const float4* Wsrc = (const float4*)(W + kh * 64 * 128);
    float4* Wd = (float4*)Wl;
#pragma unroll
    for (int i = 0; i < 8; ++i) Wd[tid + i * 256] = Wsrc[tid + i * 256];
#pragma unroll
    for (int i = 0; i < 2; ++i) {
      int f4 = tid + i * 256;
      int row = f4 >> 4;
      int kq = f4 & 15;
      float4 v = *(const float4*)(A + (size_t)(rbase + row) * 128 + kh * 64 + kq * 4);
      At[(kq * 4 + 0) * 36 + row] = v.x;
      At[(kq * 4 + 1) * 36 + row] = v.y;
      At[(kq * 4 + 2) * 36 + row] = v.z;
      At[(kq * 4 + 3) * 36 + row] = v.w;
    }
    __syncthreads();
#pragma unroll 4
    for (int k = 0; k < 64; ++k) {
      float4 alo = *(const float4*)&At[k * 36 + r0];
      float4 ahi = *(const float4*)&At[k * 36 + r0 + 4];
      float2 w = *(const float2*)&Wl[k * 128 + lane * 2];
      acc0[0] += alo.x * w.x; acc1[0] += alo.x * w.y;
      acc0[1] += alo.y * w.x; acc1[1] += alo.y * w.y;
      acc0[2] += alo.z * w.x; acc1[2] += alo.z * w.y;
      acc0[3] += alo.w * w.x; acc1[3] += alo.w * w.y;
      acc0[4] += ahi.x * w.x; acc1[4] += ahi.x * w.y;
      acc0[5] += ahi.y * w.x; acc1[5] += ahi.y * w.y;
      acc0[6] += ahi.z * w.x; acc1[6] += ahi.z * w.y;
      acc0[7] += ahi.w * w.x; acc1[7] += ahi.w * w.y;
    }
    __syncthreads();
  }
#pragma unroll
  for (int i = 0; i < 8; ++i) {
    int row = rbase + r0 + i;
    float2 v = make_float2(acc0[i], acc1[i]);
    *(float2*)(O + (size_t)row * 128 + lane * 2) = v;
  }
}

// ---------------- fused GEMM (layers 2,3): A-staging applies BN+ReLU (writes X)
// then dropout (threefry) and uses the dropped values as the GEMM A operand.
__global__ __launch_bounds__(256) void gemm_fused(const float* __restrict__ AGG,
                                                  const float* __restrict__ sums,
                                                  const float* __restrict__ g,
                                                  const float* __restrict__ bt,
                                                  const float* __restrict__ W,
                                                  float* __restrict__ X,
                                                  float* __restrict__ O,
                                                  uint32_t k0, uint32_t k1) {
  __shared__ __align__(16) float Wl[64 * 128];
  __shared__ __align__(16) float At[64 * 36];
  const int tid = threadIdx.x;
  const int lane = tid & 63;
  const int wv = tid >> 6;
  const int rbase = blockIdx.x * 32;
  const int r0 = wv * 8;

  float acc0[8], acc1[8];
#pragma unroll
  for (int i = 0; i < 8; ++i) { acc0[i] = 0.f; acc1[i] = 0.f; }

  for (int kh = 0; kh < 2; ++kh) {
    const float4* Wsrc = (const float4*)(W + kh * 64 * 128);
    float4* Wd = (float4*)Wl;
#pragma unroll
    for (int i = 0; i < 8; ++i) Wd[tid + i * 256] = Wsrc[tid + i * 256];
#pragma unroll
    for (int i = 0; i < 2; ++i) {
      int f4 = tid + i * 256;
      int row = f4 >> 4;
      int kq = f4 & 15;
      int c0 = kh * 64 + kq * 4;
      int grow = rbase + row;
      float4 a = *(const float4*)(AGG + (size_t)grow * 128 + c0);
      float y[4], hd[4];
#pragma unroll
      for (int jj = 0; jj < 4; ++jj) {
        int c = c0 + jj;
        float mu = sums[c] * (1.0f / N_NODES);
        float var = fmaxf(sums[128 + c] * (1.0f / N_NODES) - mu * mu, 0.f);
        float inv = rsqrtf(var + BN_EPS);
        float av = ((const float*)&a)[jj];
        float yv = fmaxf(g[c] * (av - mu) * inv + bt[c], 0.f);
        uint32_t bits = jax_bits32(k0, k1, (uint32_t)(grow * 128 + c));
        y[jj] = yv;
        hd[jj] = (bits & 0x80000000u) ? 0.f : 2.f * yv;
      }
      *(float4*)(X + (size_t)grow * 128 + c0) = *(float4*)y;
      At[(c0 - kh * 64 + 0) * 36 + row] = hd[0];
      At[(c0 - kh * 64 + 1) * 36 + row] = hd[1];
      At[(c0 - kh * 64 + 2) * 36 + row] = hd[2];
      At[(c0 - kh * 64 + 3) * 36 + row] = hd[3];
    }
    __syncthreads();
#pragma unroll 4
    for (int k = 0; k < 64; ++k) {
      float4 alo = *(const float4*)&At[k * 36 + r0];
      float4 ahi = *(const float4*)&At[k * 36 + r0 + 4];
      float2 w = *(const float2*)&Wl[k * 128 + lane * 2];
      acc0[0] += alo.x * w.x; acc1[0] += alo.x * w.y;
      acc0[1] += alo.y * w.x; acc1[1] += alo.y * w.y;
      acc0[2] += alo.z * w.x; acc1[2] += alo.z * w.y;
      acc0[3] += alo.w * w.x; acc1[3] += alo.w * w.y;
      acc0[4] += ahi.x * w.x; acc1[4] += ahi.x * w.y;
      acc0[5] += ahi.y * w.x; acc1[5] += ahi.y * w.y;
      acc0[6] += ahi.z * w.x; acc1[6] += ahi.z * w.y;
      acc0[7] += ahi.w * w.x; acc1[7] += ahi.w * w.y;
    }
    __syncthreads();
  }
#pragma unroll
  for (int i = 0; i < 8; ++i) {
    int row = rbase + r0 + i;
    float2 v = make_float2(acc0[i], acc1[i]);
    *(float2*)(O + (size_t)row * 128 + lane * 2) = v;
  }
}

// ---------------- CSR build ----------------
__global__ __launch_bounds__(256) void csr_count(const int* __restrict__ ei,
                                                 int* __restrict__ cnt) {
  int e = blockIdx.x * 256 + threadIdx.x;
  if (e < N_EDGES) atomicAdd(&cnt[ei[e + N_EDGES]], 1);
}

__global__ __launch_bounds__(256) void scan_blocks(int* __restrict__ cnt,
                                                   int* __restrict__ bsum) {
  __shared__ int tmp[256];
  int tid = threadIdx.x;
  int i = blockIdx.x * 256 + tid;
  int v = (i < N_NODES) ? cnt[i] : 0;
  tmp[tid] = v;
  __syncthreads();
  for (int off = 1; off < 256; off <<= 1) {
    int t = (tid >= off) ? tmp[tid - off] : 0;
    __syncthreads();
    if (tid >= off) tmp[tid] += t;
    __syncthreads();
  }
  if (i < N_NODES) cnt[i] = tmp[tid] - v;
  if (tid == 255) bsum[blockIdx.x] = tmp[255];
}

__global__ __launch_bounds__(512) void scan_bsum(int* __restrict__ bsum, int nb) {
  __shared__ int tmp[512];
  int tid = threadIdx.x;
  int v = (tid < nb) ? bsum[tid] : 0;
  tmp[tid] = v;
  __syncthreads();
  for (int off = 1; off < 512; off <<= 1) {
    int t = (tid >= off) ? tmp[tid - off] : 0;
    __syncthreads();
    if (tid >= off) tmp[tid] += t;
    __syncthreads();
  }
  if (tid < nb) bsum[tid] = tmp[tid] - v;
}

__global__ __launch_bounds__(256) void add_offsets(int* __restrict__ cnt,
                                                   const int* __restrict__ bsum,
                                                   int* __restrict__ row_ptr) {
  int i = blockIdx.x * 256 + threadIdx.x;
  if (i < N_NODES) {
    int r = cnt[i] + bsum[blockIdx.x];
    row_ptr[i] = r;
    cnt[i] = r;
  }
  if (i == 0) row_ptr[N_NODES] = N_EDGES;
}

// fill interleaved (src, w_bits) pairs
__global__ __launch_bounds__(256) void csr_fill(const int* __restrict__ ei,
                                                const float* __restrict__ ew,
                                                int* __restrict__ cursor,
                                                int2* __restrict__ edges) {
  int e = blockIdx.x * 256 + threadIdx.x;
  if (e < N_EDGES) {
    int d = ei[e + N_EDGES];
    int p = atomicAdd(&cursor[d], 1);
    edges[p] = make_int2(ei[e], __float_as_int(ew[e]));
  }
}

// ---------------- gather aggregation: AGG[n] = b + sum_{e->n} w_e * H[src_e]
// 1 node per 64-lane wave (lane owns channels 2l,2l+1); 4 waves/block; no barriers.
__global__ __launch_bounds__(256) void gather_agg(const float* __restrict__ H,
                                                  const int* __restrict__ row_ptr,
                                                  const int2* __restrict__ edges,
                                                  const float* __restrict__ bias,
                                                  float* __restrict__ AGG) {
  const int node = blockIdx.x * 4 + (threadIdx.x >> 6);
  const int lane = threadIdx.x & 63;
  float2 acc = *(const float2*)(bias + lane * 2);
  const int beg = row_ptr[node];
  const int end = row_ptr[node + 1];
  int j = beg;
  for (; j + 3 < end; j += 4) {
    int2 e0 = edges[j + 0];
    int2 e1 = edges[j + 1];
    int2 e2 = edges[j + 2];
    int2 e3 = edges[j + 3];
    float2 v0 = *(const float2*)(H + (size_t)e0.x * 128 + lane * 2);
    float2 v1 = *(const float2*)(H + (size_t)e1.x * 128 + lane * 2);
    float2 v2 = *(const float2*)(H + (size_t)e2.x * 128 + lane * 2);
    float2 v3 = *(const float2*)(H + (size_t)e3.x * 128 + lane * 2);
    float w0 = __int_as_float(e0.y), w1 = __int_as_float(e1.y);
    float w2 = __int_as_float(e2.y), w3 = __int_as_float(e3.y);
    acc.x += w0 * v0.x + w1 * v1.x + w2 * v2.x + w3 * v3.x;
    acc.y += w0 * v0.y + w1 * v1.y + w2 * v2.y + w3 * v3.y;
  }
  for (; j < end; ++j) {
    int2 e = edges[j];
    float2 v = *(const float2*)(H + (size_t)e.x * 128 + lane * 2);
    float w = __int_as_float(e.y);
    acc.x += w * v.x;
    acc.y += w * v.y;
  }
  *(float2*)(AGG + (size_t)node * 128 + lane * 2) = acc;
}

// ---------------- BN stats: per-channel sum & sumsq -> per-block partials
__global__ __launch_bounds__(256) void bn_stats(const float* __restrict__ H,
                                                float* __restrict__ partials) {
  const int c4 = (threadIdx.x & 31) * 4;
  const int rg = threadIdx.x >> 5;              // 0..7
  float4 s = make_float4(0.f, 0.f, 0.f, 0.f);
  float4 q = make_float4(0.f, 0.f, 0.f, 0.f);
  for (int row = blockIdx.x * 8 + rg; row < N_NODES; row += gridDim.x * 8) {
    float4 v = *(const float4*)(H + (size_t)row * 128 + c4);
    s.x += v.x; s.y += v.y; s.z += v.z; s.w += v.w;
    q.x += v.x * v.x; q.y += v.y * v.y; q.z += v.z * v.z; q.w += v.w * v.w;
  }
  __shared__ float ls[8][256];
  *(float4*)&ls[rg][c4] = s;
  *(float4*)&ls[rg][128 + c4] = q;
  __syncthreads();
  float t = 0.f;
#pragma unroll
  for (int g = 0; g < 8; ++g) t += ls[g][threadIdx.x];
  partials[blockIdx.x * 256 + threadIdx.x] = t;
}

// sum nblk partial blocks of 256 floats into sums[256]
__global__ __launch_bounds__(256) void reduce_partials(const float* __restrict__ partials,
                                                       float* __restrict__ sums, int nblk) {
  float s = 0.f;
  for (int b = blockIdx.x; b < nblk; b += gridDim.x)
    s += partials[b * 256 + threadIdx.x];
  unsafeAtomicAdd(&sums[threadIdx.x], s);
}

// ---------------- jk = max(x1,x2,x3); OUT = log_softmax(jk @ Wf + bf)
// lane = output COLUMN; wave owns 8 rows with 8 named SCALAR accumulators
// (per-lane scalars cannot be fissioned/spilled like the 64-deep per-lane array).
// W[k*64+lane]: coalesced, 32KB L1-hot. Row loads: wave-uniform float4 (1 txn).
// log_softmax: 64-lane shuffle reduce per row (known-good from r3-r5).
__global__ __launch_bounds__(256) void jk_final(const float* __restrict__ X1,
                                                const float* __restrict__ X2,
                                                const float* __restrict__ X3,
                                                const float* __restrict__ Wf,
                                                const float* __restrict__ bf,
                                                float* __restrict__ OUT) {
  const int lane = threadIdx.x & 63;
  const int wv = threadIdx.x >> 6;
  const int rbase = (blockIdx.x * 4 + wv) * 8;     // 3125 blocks * 32 rows = 100000

  float a0, a1, a2, a3, a4, a5, a6, a7;
  {
    float b = bf[lane];
    a0 = b; a1 = b; a2 = b; a3 = b; a4 = b; a5 = b; a6 = b; a7 = b;
  }

  const float* p1 = X1 + (size_t)rbase * 128;
  const float* p2 = X2 + (size_t)rbase * 128;
  const float* p3 = X3 + (size_t)rbase * 128;

  for (int k4 = 0; k4 < 32; ++k4) {
    const int ko = k4 * 4;
    float w0 = Wf[(ko + 0) * 64 + lane];
    float w1 = Wf[(ko + 1) * 64 + lane];
    float w2 = Wf[(ko + 2) * 64 + lane];
    float w3 = Wf[(ko + 3) * 64 + lane];
#define ROW_FMA(r, accr) {                                              \
    float4 xa = *(const float4*)(p1 + (r) * 128 + ko);                  \
    float4 xb = *(const float4*)(p2 + (r) * 128 + ko);                  \
    float4 xc = *(const float4*)(p3 + (r) * 128 + ko);                  \
    float j0 = fmaxf(fmaxf(xa.x, xb.x), xc.x);                          \
    float j1 = fmaxf(fmaxf(xa.y, xb.y), xc.y);                          \
    float j2 = fmaxf(fmaxf(xa.z, xb.z), xc.z);                          \
    float j3 = fmaxf(fmaxf(xa.w, xb.w), xc.w);                          \
    accr = fmaf(j0, w0, accr);                                          \
    accr = fmaf(j1, w1, accr);                                          \
    accr = fmaf(j2, w2, accr);                                          \
    accr = fmaf(j3, w3, accr); }
    ROW_FMA(0, a0) ROW_FMA(1, a1) ROW_FMA(2, a2) ROW_FMA(3, a3)
    ROW_FMA(4, a4) ROW_FMA(5, a5) ROW_FMA(6, a6) ROW_FMA(7, a7)
#undef ROW_FMA
  }

  // per-row log_softmax across the 64 lanes (cols), then store
#define ROW_SM(r, accr) {                                               \
    float v = accr;                                                     \
    float m = v;                                                        \
    _Pragma("unroll")                                                   \
    for (int s = 32; s > 0; s >>= 1) m = fmaxf(m, __shfl_xor(m, s));    \
    float e = expf(v - m);                                              \
    float sum = e;                                                      \
    _Pragma("unroll")                                                   \
    for (int s = 32; s > 0; s >>= 1) sum += __shfl_xor(sum, s);         \
    OUT[(size_t)(rbase + (r)) * 64 + lane] = v - m - logf(sum); }
  ROW_SM(0, a0) ROW_SM(1, a1) ROW_SM(2, a2) ROW_SM(3, a3)
  ROW_SM(4, a4) ROW_SM(5, a5) ROW_SM(6, a6) ROW_SM(7, a7)
#undef ROW_SM
}

extern "C" void kernel_launch(void* const* d_in, const int* in_sizes, int n_in,
                              void* d_out, int out_size, void* d_ws, size_t ws_size,
                              hipStream_t stream) {
  const float* x   = (const float*)d_in[0];
  const int*   ei  = (const int*)d_in[1];
  const float* ew  = (const float*)d_in[2];
  const float* W1  = (const float*)d_in[3];
  const float* b1  = (const float*)d_in[4];
  const float* W2  = (const float*)d_in[5];
  const float* b2  = (const float*)d_in[6];
  const float* W3  = (const float*)d_in[7];
  const float* b3  = (const float*)d_in[8];
  const float* g1  = (const float*)d_in[9];
  const float* bt1 = (const float*)d_in[10];
  const float* g2  = (const float*)d_in[11];
  const float* bt2 = (const float*)d_in[12];
  const float* Wf  = (const float*)d_in[13];
  const float* bfb = (const float*)d_in[14];
  float* out = (float*)d_out;

  float* B0 = (float*)d_ws;
  float* B1 = B0 + NELEMS;
  float* B2 = B1 + NELEMS;
  float* B3 = B2 + NELEMS;
  float* sums = B3 + NELEMS;               // 512 floats: [0..255]=layer1, [256..511]=layer2
  int2* edges = (int2*)(sums + 512);       // N_EDGES int2 (8B-aligned)
  int* cursor = (int*)(edges + N_EDGES);   // N_NODES
  int* row_ptr = cursor + N_NODES;         // N_NODES+1
  int* bsum = row_ptr + N_NODES + 1;       // 512
  float* partials = (float*)(bsum + 512);  // 2048*256 floats (2MB)
  float* sums1 = sums;
  float* sums2 = sums + 256;

  // JAX partitionable split of key(42)=(0,42): k_i = threefry(key, (0,i)) full pair
  uint32_t k1_0, k1_1, k2_0, k2_1;
  threefry2x32(0u, 42u, 0u, 0u, k1_0, k1_1);
  threefry2x32(0u, 42u, 0u, 1u, k2_0, k2_1);

  const int GEMM_GRID = N_NODES / 32;              // 3125
  const int EDGE_GRID = (N_EDGES + 255) / 256;     // 2344
  const int NODE_GRID = (N_NODES + 255) / 256;     // 391
  const int AGG_GRID  = N_NODES / 4;               // 25000 (1 node/wave, 4 waves/block)
  const int STAT_GRID = 2048;
  const int RED_GRID  = 16;
  const int FINAL_GRID = N_NODES / 32;             // 3125 (4 waves x 8 rows)

  // ---- CSR build (reused by all 3 layers)
  hipMemsetAsync(cursor, 0, N_NODES * sizeof(int), stream);
  hipMemsetAsync(sums, 0, 512 * sizeof(float), stream);
  csr_count<<<EDGE_GRID, 256, 0, stream>>>(ei, cursor);
  scan_blocks<<<NODE_GRID, 256, 0, stream>>>(cursor, bsum);
  scan_bsum<<<1, 512, 0, stream>>>(bsum, NODE_GRID);
  add_offsets<<<NODE_GRID, 256, 0, stream>>>(cursor, bsum, row_ptr);
  csr_fill<<<EDGE_GRID, 256, 0, stream>>>(ei, ew, cursor, edges);

  // ---- layer 1: P1 = x@W1 ; AGG1 = gather(P1)+b1 ; stats1
  gemm_nk128<<<GEMM_GRID, 256, 0, stream>>>(x, W1, B0);
  gather_agg<<<AGG_GRID, 256, 0, stream>>>(B0, row_ptr, edges, b1, B1);
  bn_stats<<<STAT_GRID, 256, 0, stream>>>(B1, partials);
  reduce_partials<<<RED_GRID, 256, 0, stream>>>(partials, sums1, STAT_GRID);
  // ---- layer 2: fused BN1+ReLU (-> X1=B2) + dropout(k1) + GEMM W2 -> P2=B0
  gemm_fused<<<GEMM_GRID, 256, 0, stream>>>(B1, sums1, g1, bt1, W2, B2, B0, k1_0, k1_1);
  gather_agg<<<AGG_GRID, 256, 0, stream>>>(B0, row_ptr, edges, b2, B1);
  bn_stats<<<STAT_GRID, 256, 0, stream>>>(B1, partials);
  reduce_partials<<<RED_GRID, 256, 0, stream>>>(partials, sums2, STAT_GRID);
  // ---- layer 3: fused BN2+ReLU (-> X2=B3) + dropout(k2) + GEMM W3 -> P3=B0
  gemm_fused<<<GEMM_GRID, 256, 0, stream>>>(B1, sums2, g2, bt2, W3, B3, B0, k2_0, k2_1);
  gather_agg<<<AGG_GRID, 256, 0, stream>>>(B0, row_ptr, edges, b3, B1);
  // ---- JK max + final linear + log_softmax
  jk_final<<<FINAL_GRID, 256, 0, stream>>>(B2, B3, B1, Wf, bfb, out);
}

// Round 11
// 589.068 us; speedup vs baseline: 1.3921x; 1.3921x over previous
//
#include <hip/hip_runtime.h>
#include <stdint.h>

#define N_NODES 100000
#define N_EDGES 600000
#define HID 128
#define OUT_C 64
#define NELEMS 12800000      // 100000*128
#define BN_EPS 1e-5f

// ---------------- threefry2x32 (matches JAX) ----------------
__device__ __host__ __forceinline__ void threefry2x32(uint32_t k0, uint32_t k1,
                                                      uint32_t x0, uint32_t x1,
                                                      uint32_t& o0, uint32_t& o1) {
  uint32_t ks0 = k0, ks1 = k1, ks2 = k0 ^ k1 ^ 0x1BD11BDAu;
  x0 += ks0; x1 += ks1;
#define TFR(r) { x0 += x1; x1 = (x1 << (r)) | (x1 >> (32 - (r))); x1 ^= x0; }
  TFR(13) TFR(15) TFR(26) TFR(6)
  x0 += ks1; x1 += ks2 + 1u;
  TFR(17) TFR(29) TFR(16) TFR(24)
  x0 += ks2; x1 += ks0 + 2u;
  TFR(13) TFR(15) TFR(26) TFR(6)
  x0 += ks0; x1 += ks1 + 3u;
  TFR(17) TFR(29) TFR(16) TFR(24)
  x0 += ks1; x1 += ks2 + 4u;
  TFR(13) TFR(15) TFR(26) TFR(6)
  x0 += ks2; x1 += ks0 + 5u;
#undef TFR
  o0 = x0; o1 = x1;
}

// JAX threefry_partitionable random_bits for flat index i: out0^out1 of threefry(key,(0,i))
__device__ __forceinline__ uint32_t jax_bits32(uint32_t k0, uint32_t k1, uint32_t i) {
  uint32_t b0, b1;
  threefry2x32(k0, k1, 0u, i, b0, b1);
  return b0 ^ b1;
}

// ---------------- plain GEMM (layer 1): O[r][c] = sum_k A[r][k]*W[k][c]
__global__ __launch_bounds__(256) void gemm_nk128(const float* __restrict__ A,
                                                  const float* __restrict__ W,
                                                  float* __restrict__ O) {
  __shared__ __align__(16) float Wl[64 * 128];
  __shared__ __align__(16) float At[64 * 36];
  const int tid = threadIdx.x;
  const int lane = tid & 63;
  const int wv = tid >> 6;
  const int rbase = blockIdx.x * 32;
  const int r0 = wv * 8;

  float acc0[8], acc1[8];
#pragma unroll
  for (int i = 0; i < 8; ++i) { acc0[i] = 0.f; acc1[i] = 0.f; }

  for (int kh = 0; kh < 2; ++kh) {
    const float4* Wsrc = (const float4*)(W + kh * 64 * 128);
    float4* Wd = (float4*)Wl;
#pragma unroll
    for (int i = 0; i < 8; ++i) Wd[tid + i * 256] = Wsrc[tid + i * 256];
#pragma unroll
    for (int i = 0; i < 2; ++i) {
      int f4 = tid + i * 256;
      int row = f4 >> 4;
      int kq = f4 & 15;
      float4 v = *(const float4*)(A + (size_t)(rbase + row) * 128 + kh * 64 + kq * 4);
      At[(kq * 4 + 0) * 36 + row] = v.x;
      At[(kq * 4 + 1) * 36 + row] = v.y;
      At[(kq * 4 + 2) * 36 + row] = v.z;
      At[(kq * 4 + 3) * 36 + row] = v.w;
    }
    __syncthreads();
#pragma unroll 4
    for (int k = 0; k < 64; ++k) {
      float4 alo = *(const float4*)&At[k * 36 + r0];
      float4 ahi = *(const float4*)&At[k * 36 + r0 + 4];
      float2 w = *(const float2*)&Wl[k * 128 + lane * 2];
      acc0[0] += alo.x * w.x; acc1[0] += alo.x * w.y;
      acc0[1] += alo.y * w.x; acc1[1] += alo.y * w.y;
      acc0[2] += alo.z * w.x; acc1[2] += alo.z * w.y;
      acc0[3] += alo.w * w.x; acc1[3] += alo.w * w.y;
      acc0[4] += ahi.x * w.x; acc1[4] += ahi.x * w.y;
      acc0[5] += ahi.y * w.x; acc1[5] += ahi.y * w.y;
      acc0[6] += ahi.z * w.x; acc1[6] += ahi.z * w.y;
      acc0[7] += ahi.w * w.x; acc1[7] += ahi.w * w.y;
    }
    __syncthreads();
  }
#pragma unroll
  for (int i = 0; i < 8; ++i) {
    int row = rbase + r0 + i;
    float2 v = make_float2(acc0[i], acc1[i]);
    *(float2*)(O + (size_t)row * 128 + lane * 2) = v;
  }
}

// ---------------- fused GEMM (layers 2,3): A-staging applies BN+ReLU (writes X)
// then dropout (threefry) and uses the dropped values as the GEMM A operand.
__global__ __launch_bounds__(256) void gemm_fused(const float* __restrict__ AGG,
                                                  const float* __restrict__ sums,
                                                  const float* __restrict__ g,
                                                  const float* __restrict__ bt,
                                                  const float* __restrict__ W,
                                                  float* __restrict__ X,
                                                  float* __restrict__ O,
                                                  uint32_t k0, uint32_t k1) {
  __shared__ __align__(16) float Wl[64 * 128];
  __shared__ __align__(16) float At[64 * 36];
  const int tid = threadIdx.x;
  const int lane = tid & 63;
  const int wv = tid >> 6;
  const int rbase = blockIdx.x * 32;
  const int r0 = wv * 8;

  float acc0[8], acc1[8];
#pragma unroll
  for (int i = 0; i < 8; ++i) { acc0[i] = 0.f; acc1[i] = 0.f; }

  for (int kh = 0; kh < 2; ++kh) {
    const float4* Wsrc = (const float4*)(W + kh * 64 * 128);
    float4* Wd = (float4*)Wl;
#pragma unroll
    for (int i = 0; i < 8; ++i) Wd[tid + i * 256] = Wsrc[tid + i * 256];
#pragma unroll
    for (int i = 0; i < 2; ++i) {
      int f4 = tid + i * 256;
      int row = f4 >> 4;
      int kq = f4 & 15;
      int c0 = kh * 64 + kq * 4;
      int grow = rbase + row;
      float4 a = *(const float4*)(AGG + (size_t)grow * 128 + c0);
      float y[4], hd[4];
#pragma unroll
      for (int jj = 0; jj < 4; ++jj) {
        int c = c0 + jj;
        float mu = sums[c] * (1.0f / N_NODES);
        float var = fmaxf(sums[128 + c] * (1.0f / N_NODES) - mu * mu, 0.f);
        float inv = rsqrtf(var + BN_EPS);
        float av = ((const float*)&a)[jj];
        float yv = fmaxf(g[c] * (av - mu) * inv + bt[c], 0.f);
        uint32_t bits = jax_bits32(k0, k1, (uint32_t)(grow * 128 + c));
        y[jj] = yv;
        hd[jj] = (bits & 0x80000000u) ? 0.f : 2.f * yv;
      }
      *(float4*)(X + (size_t)grow * 128 + c0) = *(float4*)y;
      At[(c0 - kh * 64 + 0) * 36 + row] = hd[0];
      At[(c0 - kh * 64 + 1) * 36 + row] = hd[1];
      At[(c0 - kh * 64 + 2) * 36 + row] = hd[2];
      At[(c0 - kh * 64 + 3) * 36 + row] = hd[3];
    }
    __syncthreads();
#pragma unroll 4
    for (int k = 0; k < 64; ++k) {
      float4 alo = *(const float4*)&At[k * 36 + r0];
      float4 ahi = *(const float4*)&At[k * 36 + r0 + 4];
      float2 w = *(const float2*)&Wl[k * 128 + lane * 2];
      acc0[0] += alo.x * w.x; acc1[0] += alo.x * w.y;
      acc0[1] += alo.y * w.x; acc1[1] += alo.y * w.y;
      acc0[2] += alo.z * w.x; acc1[2] += alo.z * w.y;
      acc0[3] += alo.w * w.x; acc1[3] += alo.w * w.y;
      acc0[4] += ahi.x * w.x; acc1[4] += ahi.x * w.y;
      acc0[5] += ahi.y * w.x; acc1[5] += ahi.y * w.y;
      acc0[6] += ahi.z * w.x; acc1[6] += ahi.z * w.y;
      acc0[7] += ahi.w * w.x; acc1[7] += ahi.w * w.y;
    }
    __syncthreads();
  }
#pragma unroll
  for (int i = 0; i < 8; ++i) {
    int row = rbase + r0 + i;
    float2 v = make_float2(acc0[i], acc1[i]);
    *(float2*)(O + (size_t)row * 128 + lane * 2) = v;
  }
}

// ---------------- CSR build ----------------
__global__ __launch_bounds__(256) void csr_count(const int* __restrict__ ei,
                                                 int* __restrict__ cnt) {
  int e = blockIdx.x * 256 + threadIdx.x;
  if (e < N_EDGES) atomicAdd(&cnt[ei[e + N_EDGES]], 1);
}

__global__ __launch_bounds__(256) void scan_blocks(int* __restrict__ cnt,
                                                   int* __restrict__ bsum) {
  __shared__ int tmp[256];
  int tid = threadIdx.x;
  int i = blockIdx.x * 256 + tid;
  int v = (i < N_NODES) ? cnt[i] : 0;
  tmp[tid] = v;
  __syncthreads();
  for (int off = 1; off < 256; off <<= 1) {
    int t = (tid >= off) ? tmp[tid - off] : 0;
    __syncthreads();
    if (tid >= off) tmp[tid] += t;
    __syncthreads();
  }
  if (i < N_NODES) cnt[i] = tmp[tid] - v;
  if (tid == 255) bsum[blockIdx.x] = tmp[255];
}

__global__ __launch_bounds__(512) void scan_bsum(int* __restrict__ bsum, int nb) {
  __shared__ int tmp[512];
  int tid = threadIdx.x;
  int v = (tid < nb) ? bsum[tid] : 0;
  tmp[tid] = v;
  __syncthreads();
  for (int off = 1; off < 512; off <<= 1) {
    int t = (tid >= off) ? tmp[tid - off] : 0;
    __syncthreads();
    if (tid >= off) tmp[tid] += t;
    __syncthreads();
  }
  if (tid < nb) bsum[tid] = tmp[tid] - v;
}

__global__ __launch_bounds__(256) void add_offsets(int* __restrict__ cnt,
                                                   const int* __restrict__ bsum,
                                                   int* __restrict__ row_ptr) {
  int i = blockIdx.x * 256 + threadIdx.x;
  if (i < N_NODES) {
    int r = cnt[i] + bsum[blockIdx.x];
    row_ptr[i] = r;
    cnt[i] = r;
  }
  if (i == 0) row_ptr[N_NODES] = N_EDGES;
}

// fill interleaved (src, w_bits) pairs
__global__ __launch_bounds__(256) void csr_fill(const int* __restrict__ ei,
                                                const float* __restrict__ ew,
                                                int* __restrict__ cursor,
                                                int2* __restrict__ edges) {
  int e = blockIdx.x * 256 + threadIdx.x;
  if (e < N_EDGES) {
    int d = ei[e + N_EDGES];
    int p = atomicAdd(&cursor[d], 1);
    edges[p] = make_int2(ei[e], __float_as_int(ew[e]));
  }
}

// ---------------- gather aggregation: AGG[n] = b + sum_{e->n} w_e * H[src_e]
// 1 node per 64-lane wave (lane owns channels 2l,2l+1); 4 waves/block; no barriers.
__global__ __launch_bounds__(256) void gather_agg(const float* __restrict__ H,
                                                  const int* __restrict__ row_ptr,
                                                  const int2* __restrict__ edges,
                                                  const float* __restrict__ bias,
                                                  float* __restrict__ AGG) {
  const int node = blockIdx.x * 4 + (threadIdx.x >> 6);
  const int lane = threadIdx.x & 63;
  float2 acc = *(const float2*)(bias + lane * 2);
  const int beg = row_ptr[node];
  const int end = row_ptr[node + 1];
  int j = beg;
  for (; j + 3 < end; j += 4) {
    int2 e0 = edges[j + 0];
    int2 e1 = edges[j + 1];
    int2 e2 = edges[j + 2];
    int2 e3 = edges[j + 3];
    float2 v0 = *(const float2*)(H + (size_t)e0.x * 128 + lane * 2);
    float2 v1 = *(const float2*)(H + (size_t)e1.x * 128 + lane * 2);
    float2 v2 = *(const float2*)(H + (size_t)e2.x * 128 + lane * 2);
    float2 v3 = *(const float2*)(H + (size_t)e3.x * 128 + lane * 2);
    float w0 = __int_as_float(e0.y), w1 = __int_as_float(e1.y);
    float w2 = __int_as_float(e2.y), w3 = __int_as_float(e3.y);
    acc.x += w0 * v0.x + w1 * v1.x + w2 * v2.x + w3 * v3.x;
    acc.y += w0 * v0.y + w1 * v1.y + w2 * v2.y + w3 * v3.y;
  }
  for (; j < end; ++j) {
    int2 e = edges[j];
    float2 v = *(const float2*)(H + (size_t)e.x * 128 + lane * 2);
    float w = __int_as_float(e.y);
    acc.x += w * v.x;
    acc.y += w * v.y;
  }
  *(float2*)(AGG + (size_t)node * 128 + lane * 2) = acc;
}

// ---------------- BN stats: per-channel sum & sumsq -> per-block partials
__global__ __launch_bounds__(256) void bn_stats(const float* __restrict__ H,
                                                float* __restrict__ partials) {
  const int c4 = (threadIdx.x & 31) * 4;
  const int rg = threadIdx.x >> 5;              // 0..7
  float4 s = make_float4(0.f, 0.f, 0.f, 0.f);
  float4 q = make_float4(0.f, 0.f, 0.f, 0.f);
  for (int row = blockIdx.x * 8 + rg; row < N_NODES; row += gridDim.x * 8) {
    float4 v = *(const float4*)(H + (size_t)row * 128 + c4);
    s.x += v.x; s.y += v.y; s.z += v.z; s.w += v.w;
    q.x += v.x * v.x; q.y += v.y * v.y; q.z += v.z * v.z; q.w += v.w * v.w;
  }
  __shared__ float ls[8][256];
  *(float4*)&ls[rg][c4] = s;
  *(float4*)&ls[rg][128 + c4] = q;
  __syncthreads();
  float t = 0.f;
#pragma unroll
  for (int g = 0; g < 8; ++g) t += ls[g][threadIdx.x];
  partials[blockIdx.x * 256 + threadIdx.x] = t;
}

// sum nblk partial blocks of 256 floats into sums[256]
__global__ __launch_bounds__(256) void reduce_partials(const float* __restrict__ partials,
                                                       float* __restrict__ sums, int nblk) {
  float s = 0.f;
  for (int b = blockIdx.x; b < nblk; b += gridDim.x)
    s += partials[b * 256 + threadIdx.x];
  unsafeAtomicAdd(&sums[threadIdx.x], s);
}

// ---------------- jk = max(x1,x2,x3); OUT = log_softmax(jk @ Wf + bf)
// ROUND-3 KNOWN-GOOD (69us): 16 rows/block; wave w -> rows {w, w+4, w+8, w+12};
// W + J staged in LDS; shuffle log_softmax. Three "improved" register/uniform-load
// variants all regressed (99/108/308us) -- do not touch again.
__global__ __launch_bounds__(256) void jk_final(const float* __restrict__ X1,
                                                const float* __restrict__ X2,
                                                const float* __restrict__ X3,
                                                const float* __restrict__ Wf,
                                                const float* __restrict__ bf,
                                                float* __restrict__ OUT) {
  __shared__ __align__(16) float Wl[128 * 64];
  __shared__ __align__(16) float Jl[16][128];
  int tid = threadIdx.x;
  int lane = tid & 63;
  int wv = tid >> 6;
  int rbase = blockIdx.x * 16;
  {
    const float4* ws = (const float4*)Wf;
    float4* wd = (float4*)Wl;
#pragma unroll
    for (int i = 0; i < 8; ++i) wd[tid + i * 256] = ws[tid + i * 256];
  }
#pragma unroll
  for (int i = 0; i < 2; ++i) {
    int f4 = tid + i * 256;       // 512 float4
    int row = f4 >> 5;            // 32 float4 per row
    int q = f4 & 31;
    size_t off = (size_t)(rbase + row) * 128 + q * 4;
    float4 a = *(const float4*)(X1 + off);
    float4 b = *(const float4*)(X2 + off);
    float4 c = *(const float4*)(X3 + off);
    float4 m;
    m.x = fmaxf(fmaxf(a.x, b.x), c.x);
    m.y = fmaxf(fmaxf(a.y, b.y), c.y);
    m.z = fmaxf(fmaxf(a.z, b.z), c.z);
    m.w = fmaxf(fmaxf(a.w, b.w), c.w);
    *(float4*)&Jl[row][q * 4] = m;
  }
  __syncthreads();
  float acc[4];
  float bv = bf[lane];
#pragma unroll
  for (int j = 0; j < 4; ++j) acc[j] = bv;
#pragma unroll 4
  for (int k = 0; k < 128; k += 4) {
    float4 j0 = *(const float4*)&Jl[wv][k];
    float4 j1 = *(const float4*)&Jl[wv + 4][k];
    float4 j2 = *(const float4*)&Jl[wv + 8][k];
    float4 j3 = *(const float4*)&Jl[wv + 12][k];
#pragma unroll
    for (int kk = 0; kk < 4; ++kk) {
      float w = Wl[(k + kk) * 64 + lane];
      acc[0] += ((const float*)&j0)[kk] * w;
      acc[1] += ((const float*)&j1)[kk] * w;
      acc[2] += ((const float*)&j2)[kk] * w;
      acc[3] += ((const float*)&j3)[kk] * w;
    }
  }
#pragma unroll
  for (int j = 0; j < 4; ++j) {
    float v = acc[j];
    float m = v;
#pragma unroll
    for (int s = 32; s > 0; s >>= 1) m = fmaxf(m, __shfl_xor(m, s));
    float e = expf(v - m);
    float sum = e;
#pragma unroll
    for (int s = 32; s > 0; s >>= 1) sum += __shfl_xor(sum, s);
    OUT[(size_t)(rbase + wv + 4 * j) * 64 + lane] = v - m - logf(sum);
  }
}

extern "C" void kernel_launch(void* const* d_in, const int* in_sizes, int n_in,
                              void* d_out, int out_size, void* d_ws, size_t ws_size,
                              hipStream_t stream) {
  const float* x   = (const float*)d_in[0];
  const int*   ei  = (const int*)d_in[1];
  const float* ew  = (const float*)d_in[2];
  const float* W1  = (const float*)d_in[3];
  const float* b1  = (const float*)d_in[4];
  const float* W2  = (const float*)d_in[5];
  const float* b2  = (const float*)d_in[6];
  const float* W3  = (const float*)d_in[7];
  const float* b3  = (const float*)d_in[8];
  const float* g1  = (const float*)d_in[9];
  const float* bt1 = (const float*)d_in[10];
  const float* g2  = (const float*)d_in[11];
  const float* bt2 = (const float*)d_in[12];
  const float* Wf  = (const float*)d_in[13];
  const float* bfb = (const float*)d_in[14];
  float* out = (float*)d_out;

  float* B0 = (float*)d_ws;
  float* B1 = B0 + NELEMS;
  float* B2 = B1 + NELEMS;
  float* B3 = B2 + NELEMS;
  float* sums = B3 + NELEMS;               // 512 floats: [0..255]=layer1, [256..511]=layer2
  int2* edges = (int2*)(sums + 512);       // N_EDGES int2 (8B-aligned)
  int* cursor = (int*)(edges + N_EDGES);   // N_NODES
  int* row_ptr = cursor + N_NODES;         // N_NODES+1
  int* bsum = row_ptr + N_NODES + 1;       // 512
  float* partials = (float*)(bsum + 512);  // 2048*256 floats (2MB)
  float* sums1 = sums;
  float* sums2 = sums + 256;

  // JAX partitionable split of key(42)=(0,42): k_i = threefry(key, (0,i)) full pair
  uint32_t k1_0, k1_1, k2_0, k2_1;
  threefry2x32(0u, 42u, 0u, 0u, k1_0, k1_1);
  threefry2x32(0u, 42u, 0u, 1u, k2_0, k2_1);

  const int GEMM_GRID = N_NODES / 32;              // 3125
  const int EDGE_GRID = (N_EDGES + 255) / 256;     // 2344
  const int NODE_GRID = (N_NODES + 255) / 256;     // 391
  const int AGG_GRID  = N_NODES / 4;               // 25000 (1 node/wave, 4 waves/block)
  const int STAT_GRID = 2048;
  const int RED_GRID  = 16;
  const int FINAL_GRID = N_NODES / 16;             // 6250

  // ---- CSR build (reused by all 3 layers)
  hipMemsetAsync(cursor, 0, N_NODES * sizeof(int), stream);
  hipMemsetAsync(sums, 0, 512 * sizeof(float), stream);
  csr_count<<<EDGE_GRID, 256, 0, stream>>>(ei, cursor);
  scan_blocks<<<NODE_GRID, 256, 0, stream>>>(cursor, bsum);
  scan_bsum<<<1, 512, 0, stream>>>(bsum, NODE_GRID);
  add_offsets<<<NODE_GRID, 256, 0, stream>>>(cursor, bsum, row_ptr);
  csr_fill<<<EDGE_GRID, 256, 0, stream>>>(ei, ew, cursor, edges);

  // ---- layer 1: P1 = x@W1 ; AGG1 = gather(P1)+b1 ; stats1
  gemm_nk128<<<GEMM_GRID, 256, 0, stream>>>(x, W1, B0);
  gather_agg<<<AGG_GRID, 256, 0, stream>>>(B0, row_ptr, edges, b1, B1);
  bn_stats<<<STAT_GRID, 256, 0, stream>>>(B1, partials);
  reduce_partials<<<RED_GRID, 256, 0, stream>>>(partials, sums1, STAT_GRID);
  // ---- layer 2: fused BN1+ReLU (-> X1=B2) + dropout(k1) + GEMM W2 -> P2=B0
  gemm_fused<<<GEMM_GRID, 256, 0, stream>>>(B1, sums1, g1, bt1, W2, B2, B0, k1_0, k1_1);
  gather_agg<<<AGG_GRID, 256, 0, stream>>>(B0, row_ptr, edges, b2, B1);
  bn_stats<<<STAT_GRID, 256, 0, stream>>>(B1, partials);
  reduce_partials<<<RED_GRID, 256, 0, stream>>>(partials, sums2, STAT_GRID);
  // ---- layer 3: fused BN2+ReLU (-> X2=B3) + dropout(k2) + GEMM W3 -> P3=B0
  gemm_fused<<<GEMM_GRID, 256, 0, stream>>>(B1, sums2, g2, bt2, W3, B3, B0, k2_0, k2_1);
  gather_agg<<<AGG_GRID, 256, 0, stream>>>(B0, row_ptr, edges, b3, B1);
  // ---- JK max + final linear + log_softmax
  jk_final<<<FINAL_GRID, 256, 0, stream>>>(B2, B3, B1, Wf, bfb, out);
}

// Round 12
// 519.525 us; speedup vs baseline: 1.5785x; 1.1339x over previous
//
#include <hip/hip_runtime.h>
#include <stdint.h>

#define N_NODES 100000
#define N_EDGES 600000
#define HID 128
#define OUT_C 64
#define NELEMS 12800000      // 100000*128
#define BN_EPS 1e-5f
#define LP 136               // LDS row pitch in bf16 elems (16B-aligned rows, mild bank spread)

typedef short bf16x8 __attribute__((ext_vector_type(8)));
typedef float f32x4 __attribute__((ext_vector_type(4)));

__device__ __forceinline__ unsigned short f2bf(float f) {   // RNE float->bf16
  uint32_t u = __float_as_uint(f);
  uint32_t r = u + 0x7FFFu + ((u >> 16) & 1u);
  return (unsigned short)(r >> 16);
}

// ---------------- threefry2x32 (matches JAX) ----------------
__device__ __host__ __forceinline__ void threefry2x32(uint32_t k0, uint32_t k1,
                                                      uint32_t x0, uint32_t x1,
                                                      uint32_t& o0, uint32_t& o1) {
  uint32_t ks0 = k0, ks1 = k1, ks2 = k0 ^ k1 ^ 0x1BD11BDAu;
  x0 += ks0; x1 += ks1;
#define TFR(r) { x0 += x1; x1 = (x1 << (r)) | (x1 >> (32 - (r))); x1 ^= x0; }
  TFR(13) TFR(15) TFR(26) TFR(6)
  x0 += ks1; x1 += ks2 + 1u;
  TFR(17) TFR(29) TFR(16) TFR(24)
  x0 += ks2; x1 += ks0 + 2u;
  TFR(13) TFR(15) TFR(26) TFR(6)
  x0 += ks0; x1 += ks1 + 3u;
  TFR(17) TFR(29) TFR(16) TFR(24)
  x0 += ks1; x1 += ks2 + 4u;
  TFR(13) TFR(15) TFR(26) TFR(6)
  x0 += ks2; x1 += ks0 + 5u;
#undef TFR
  o0 = x0; o1 = x1;
}

__device__ __forceinline__ uint32_t jax_bits32(uint32_t k0, uint32_t k1, uint32_t i) {
  uint32_t b0, b1;
  threefry2x32(k0, k1, 0u, i, b0, b1);
  return b0 ^ b1;
}

// ---------------- MFMA GEMM core pieces ----------------
// Block: 256 thr = 4 waves; 64 rows; wave wv -> rows [wv*16, wv*16+16).
// Per wave: 8 N-tiles x 4 K-steps of mfma_f32_16x16x32_bf16.
// A frag: lane holds A[m=lane&15][ks*32 + (lane>>4)*8 + 0..7]
// B frag: lane holds W[ks*32 + (lane>>4)*8 + 0..7][n*16 + (lane&15)]  (from Wt[c][k])
// C/D:    col = n*16 + (lane&15), row = (lane>>4)*4 + reg   [guide-verified]

__device__ __forceinline__ void stage_Wt(const float* __restrict__ W,
                                         unsigned short* Wt, int tid) {
#pragma unroll
  for (int i = 0; i < 16; ++i) {            // 4096 float4 = 128 k x 32 cq
    int f4 = tid + i * 256;
    int k = f4 >> 5;
    int cq = f4 & 31;
    float4 w = *(const float4*)(W + k * 128 + cq * 4);
    Wt[(cq * 4 + 0) * LP + k] = f2bf(w.x);
    Wt[(cq * 4 + 1) * LP + k] = f2bf(w.y);
    Wt[(cq * 4 + 2) * LP + k] = f2bf(w.z);
    Wt[(cq * 4 + 3) * LP + k] = f2bf(w.w);
  }
}

__device__ __forceinline__ void mfma_compute_store(const unsigned short* At,
                                                   const unsigned short* Wt,
                                                   float* __restrict__ O,
                                                   int rbase, int tid) {
  const int lane = tid & 63;
  const int wv = tid >> 6;
  const int m = lane & 15;
  const int kg = lane >> 4;
  f32x4 acc0 = {0,0,0,0}, acc1 = {0,0,0,0}, acc2 = {0,0,0,0}, acc3 = {0,0,0,0};
  f32x4 acc4 = {0,0,0,0}, acc5 = {0,0,0,0}, acc6 = {0,0,0,0}, acc7 = {0,0,0,0};
  const unsigned short* Arow = At + (wv * 16 + m) * LP;
#pragma unroll
  for (int ks = 0; ks < 4; ++ks) {
    bf16x8 af = *(const bf16x8*)(Arow + ks * 32 + kg * 8);
#define MF(n, accn) { bf16x8 bfr = *(const bf16x8*)(Wt + (n * 16 + m) * LP + ks * 32 + kg * 8); \
    accn = __builtin_amdgcn_mfma_f32_16x16x32_bf16(af, bfr, accn, 0, 0, 0); }
    MF(0, acc0) MF(1, acc1) MF(2, acc2) MF(3, acc3)
    MF(4, acc4) MF(5, acc5) MF(6, acc6) MF(7, acc7)
#undef MF
  }
#define ST(n, accn) {                                                    \
  _Pragma("unroll")                                                      \
  for (int j = 0; j < 4; ++j) {                                          \
    int grow = rbase + wv * 16 + kg * 4 + j;                             \
    if (grow < N_NODES) O[(size_t)grow * 128 + n * 16 + m] = accn[j];    \
  } }
  ST(0, acc0) ST(1, acc1) ST(2, acc2) ST(3, acc3)
  ST(4, acc4) ST(5, acc5) ST(6, acc6) ST(7, acc7)
#undef ST
}

// plain (layer 1): O = bf16(A) @ bf16(W)
__global__ __launch_bounds__(256) void gemm_mfma(const float* __restrict__ A,
                                                 const float* __restrict__ W,
                                                 float* __restrict__ O) {
  __shared__ __align__(16) unsigned short Wt[128 * LP];
  __shared__ __align__(16) unsigned short At[64 * LP];
  const int tid = threadIdx.x;
  const int rbase = blockIdx.x * 64;
  stage_Wt(W, Wt, tid);
#pragma unroll
  for (int i = 0; i < 8; ++i) {             // 2048 float4 = 64 r x 32 cq
    int f4 = tid + i * 256;
    int r = f4 >> 5;
    int cq = f4 & 31;
    int grow = rbase + r;
    if (grow >= N_NODES) grow = N_NODES - 1;
    float4 a = *(const float4*)(A + (size_t)grow * 128 + cq * 4);
    uint32_t p0 = (uint32_t)f2bf(a.x) | ((uint32_t)f2bf(a.y) << 16);
    uint32_t p1 = (uint32_t)f2bf(a.z) | ((uint32_t)f2bf(a.w) << 16);
    *(uint2*)(At + r * LP + cq * 4) = make_uint2(p0, p1);
  }
  __syncthreads();
  mfma_compute_store(At, Wt, O, rbase, tid);
}

// fused (layers 2,3): BN+ReLU -> X (fp32), dropout -> bf16 A operand; O = A@W
__global__ __launch_bounds__(256) void gemm_mfma_fused(const float* __restrict__ AGG,
                                                       const float* __restrict__ sums,
                                                       const float* __restrict__ g,
                                                       const float* __restrict__ bt,
                                                       const float* __restrict__ W,
                                                       float* __restrict__ X,
                                                       float* __restrict__ O,
                                                       uint32_t k0, uint32_t k1) {
  __shared__ __align__(16) unsigned short Wt[128 * LP];
  __shared__ __align__(16) unsigned short At[64 * LP];
  const int tid = threadIdx.x;
  const int rbase = blockIdx.x * 64;
  stage_Wt(W, Wt, tid);
#pragma unroll
  for (int i = 0; i < 8; ++i) {
    int f4 = tid + i * 256;
    int r = f4 >> 5;
    int cq = f4 & 31;
    int grow = rbase + r;
    bool valid = grow < N_NODES;
    int growc = valid ? grow : N_NODES - 1;
    float4 a = *(const float4*)(AGG + (size_t)growc * 128 + cq * 4);
    float y[4];
    unsigned short hd[4];
#pragma unroll
    for (int jj = 0; jj < 4; ++jj) {
      int c = cq * 4 + jj;
      float mu = sums[c] * (1.0f / N_NODES);
      float var = fmaxf(sums[128 + c] * (1.0f / N_NODES) - mu * mu, 0.f);
      float inv = rsqrtf(var + BN_EPS);
      float av = ((const float*)&a)[jj];
      float yv = fmaxf(g[c] * (av - mu) * inv + bt[c], 0.f);
      uint32_t bits = jax_bits32(k0, k1, (uint32_t)(growc * 128 + c));
      y[jj] = yv;
      hd[jj] = f2bf((bits & 0x80000000u) ? 0.f : 2.f * yv);
    }
    if (valid) *(float4*)(X + (size_t)grow * 128 + cq * 4) = *(float4*)y;
    uint32_t p0 = (uint32_t)hd[0] | ((uint32_t)hd[1] << 16);
    uint32_t p1 = (uint32_t)hd[2] | ((uint32_t)hd[3] << 16);
    *(uint2*)(At + r * LP + cq * 4) = make_uint2(p0, p1);
  }
  __syncthreads();
  mfma_compute_store(At, Wt, O, rbase, tid);
}

// ---------------- CSR build ----------------
__global__ __launch_bounds__(256) void csr_count(const int* __restrict__ ei,
                                                 int* __restrict__ cnt) {
  int e = blockIdx.x * 256 + threadIdx.x;
  if (e < N_EDGES) atomicAdd(&cnt[ei[e + N_EDGES]], 1);
}

__global__ __launch_bounds__(256) void scan_blocks(int* __restrict__ cnt,
                                                   int* __restrict__ bsum) {
  __shared__ int tmp[256];
  int tid = threadIdx.x;
  int i = blockIdx.x * 256 + tid;
  int v = (i < N_NODES) ? cnt[i] : 0;
  tmp[tid] = v;
  __syncthreads();
  for (int off = 1; off < 256; off <<= 1) {
    int t = (tid >= off) ? tmp[tid - off] : 0;
    __syncthreads();
    if (tid >= off) tmp[tid] += t;
    __syncthreads();
  }
  if (i < N_NODES) cnt[i] = tmp[tid] - v;
  if (tid == 255) bsum[blockIdx.x] = tmp[255];
}

__global__ __launch_bounds__(512) void scan_bsum(int* __restrict__ bsum, int nb) {
  __shared__ int tmp[512];
  int tid = threadIdx.x;
  int v = (tid < nb) ? bsum[tid] : 0;
  tmp[tid] = v;
  __syncthreads();
  for (int off = 1; off < 512; off <<= 1) {
    int t = (tid >= off) ? tmp[tid - off] : 0;
    __syncthreads();
    if (tid >= off) tmp[tid] += t;
    __syncthreads();
  }
  if (tid < nb) bsum[tid] = tmp[tid] - v;
}

__global__ __launch_bounds__(256) void add_offsets(int* __restrict__ cnt,
                                                   const int* __restrict__ bsum,
                                                   int* __restrict__ row_ptr) {
  int i = blockIdx.x * 256 + threadIdx.x;
  if (i < N_NODES) {
    int r = cnt[i] + bsum[blockIdx.x];
    row_ptr[i] = r;
    cnt[i] = r;
  }
  if (i == 0) row_ptr[N_NODES] = N_EDGES;
}

__global__ __launch_bounds__(256) void csr_fill(const int* __restrict__ ei,
                                                const float* __restrict__ ew,
                                                int* __restrict__ cursor,
                                                int2* __restrict__ edges) {
  int e = blockIdx.x * 256 + threadIdx.x;
  if (e < N_EDGES) {
    int d = ei[e + N_EDGES];
    int p = atomicAdd(&cursor[d], 1);
    edges[p] = make_int2(ei[e], __float_as_int(ew[e]));
  }
}

// ---------------- gather aggregation: AGG[n] = b + sum_{e->n} w_e * H[src_e]
__global__ __launch_bounds__(256) void gather_agg(const float* __restrict__ H,
                                                  const int* __restrict__ row_ptr,
                                                  const int2* __restrict__ edges,
                                                  const float* __restrict__ bias,
                                                  float* __restrict__ AGG) {
  const int node = blockIdx.x * 4 + (threadIdx.x >> 6);
  const int lane = threadIdx.x & 63;
  float2 acc = *(const float2*)(bias + lane * 2);
  const int beg = row_ptr[node];
  const int end = row_ptr[node + 1];
  int j = beg;
  for (; j + 3 < end; j += 4) {
    int2 e0 = edges[j + 0];
    int2 e1 = edges[j + 1];
    int2 e2 = edges[j + 2];
    int2 e3 = edges[j + 3];
    float2 v0 = *(const float2*)(H + (size_t)e0.x * 128 + lane * 2);
    float2 v1 = *(const float2*)(H + (size_t)e1.x * 128 + lane * 2);
    float2 v2 = *(const float2*)(H + (size_t)e2.x * 128 + lane * 2);
    float2 v3 = *(const float2*)(H + (size_t)e3.x * 128 + lane * 2);
    float w0 = __int_as_float(e0.y), w1 = __int_as_float(e1.y);
    float w2 = __int_as_float(e2.y), w3 = __int_as_float(e3.y);
    acc.x += w0 * v0.x + w1 * v1.x + w2 * v2.x + w3 * v3.x;
    acc.y += w0 * v0.y + w1 * v1.y + w2 * v2.y + w3 * v3.y;
  }
  for (; j < end; ++j) {
    int2 e = edges[j];
    float2 v = *(const float2*)(H + (size_t)e.x * 128 + lane * 2);
    float w = __int_as_float(e.y);
    acc.x += w * v.x;
    acc.y += w * v.y;
  }
  *(float2*)(AGG + (size_t)node * 128 + lane * 2) = acc;
}

// ---------------- BN stats: per-channel sum & sumsq -> per-block partials
__global__ __launch_bounds__(256) void bn_stats(const float* __restrict__ H,
                                                float* __restrict__ partials) {
  const int c4 = (threadIdx.x & 31) * 4;
  const int rg = threadIdx.x >> 5;              // 0..7
  float4 s = make_float4(0.f, 0.f, 0.f, 0.f);
  float4 q = make_float4(0.f, 0.f, 0.f, 0.f);
  for (int row = blockIdx.x * 8 + rg; row < N_NODES; row += gridDim.x * 8) {
    float4 v = *(const float4*)(H + (size_t)row * 128 + c4);
    s.x += v.x; s.y += v.y; s.z += v.z; s.w += v.w;
    q.x += v.x * v.x; q.y += v.y * v.y; q.z += v.z * v.z; q.w += v.w * v.w;
  }
  __shared__ float ls[8][256];
  *(float4*)&ls[rg][c4] = s;
  *(float4*)&ls[rg][128 + c4] = q;
  __syncthreads();
  float t = 0.f;
#pragma unroll
  for (int g = 0; g < 8; ++g) t += ls[g][threadIdx.x];
  partials[blockIdx.x * 256 + threadIdx.x] = t;
}

__global__ __launch_bounds__(256) void reduce_partials(const float* __restrict__ partials,
                                                       float* __restrict__ sums, int nblk) {
  float s = 0.f;
  for (int b = blockIdx.x; b < nblk; b += gridDim.x)
    s += partials[b * 256 + threadIdx.x];
  unsafeAtomicAdd(&sums[threadIdx.x], s);
}

// ---------------- jk = max(x1,x2,x3); OUT = log_softmax(jk @ Wf + bf)
// ROUND-3 KNOWN-GOOD (69us) -- do not touch.
__global__ __launch_bounds__(256) void jk_final(const float* __restrict__ X1,
                                                const float* __restrict__ X2,
                                                const float* __restrict__ X3,
                                                const float* __restrict__ Wf,
                                                const float* __restrict__ bf,
                                                float* __restrict__ OUT) {
  __shared__ __align__(16) float Wl[128 * 64];
  __shared__ __align__(16) float Jl[16][128];
  int tid = threadIdx.x;
  int lane = tid & 63;
  int wv = tid >> 6;
  int rbase = blockIdx.x * 16;
  {
    const float4* ws = (const float4*)Wf;
    float4* wd = (float4*)Wl;
#pragma unroll
    for (int i = 0; i < 8; ++i) wd[tid + i * 256] = ws[tid + i * 256];
  }
#pragma unroll
  for (int i = 0; i < 2; ++i) {
    int f4 = tid + i * 256;
    int row = f4 >> 5;
    int q = f4 & 31;
    size_t off = (size_t)(rbase + row) * 128 + q * 4;
    float4 a = *(const float4*)(X1 + off);
    float4 b = *(const float4*)(X2 + off);
    float4 c = *(const float4*)(X3 + off);
    float4 m;
    m.x = fmaxf(fmaxf(a.x, b.x), c.x);
    m.y = fmaxf(fmaxf(a.y, b.y), c.y);
    m.z = fmaxf(fmaxf(a.z, b.z), c.z);
    m.w = fmaxf(fmaxf(a.w, b.w), c.w);
    *(float4*)&Jl[row][q * 4] = m;
  }
  __syncthreads();
  float acc[4];
  float bv = bf[lane];
#pragma unroll
  for (int j = 0; j < 4; ++j) acc[j] = bv;
#pragma unroll 4
  for (int k = 0; k < 128; k += 4) {
    float4 j0 = *(const float4*)&Jl[wv][k];
    float4 j1 = *(const float4*)&Jl[wv + 4][k];
    float4 j2 = *(const float4*)&Jl[wv + 8][k];
    float4 j3 = *(const float4*)&Jl[wv + 12][k];
#pragma unroll
    for (int kk = 0; kk < 4; ++kk) {
      float w = Wl[(k + kk) * 64 + lane];
      acc[0] += ((const float*)&j0)[kk] * w;
      acc[1] += ((const float*)&j1)[kk] * w;
      acc[2] += ((const float*)&j2)[kk] * w;
      acc[3] += ((const float*)&j3)[kk] * w;
    }
  }
#pragma unroll
  for (int j = 0; j < 4; ++j) {
    float v = acc[j];
    float m = v;
#pragma unroll
    for (int s = 32; s > 0; s >>= 1) m = fmaxf(m, __shfl_xor(m, s));
    float e = expf(v - m);
    float sum = e;
#pragma unroll
    for (int s = 32; s > 0; s >>= 1) sum += __shfl_xor(sum, s);
    OUT[(size_t)(rbase + wv + 4 * j) * 64 + lane] = v - m - logf(sum);
  }
}

extern "C" void kernel_launch(void* const* d_in, const int* in_sizes, int n_in,
                              void* d_out, int out_size, void* d_ws, size_t ws_size,
                              hipStream_t stream) {
  const float* x   = (const float*)d_in[0];
  const int*   ei  = (const int*)d_in[1];
  const float* ew  = (const float*)d_in[2];
  const float* W1  = (const float*)d_in[3];
  const float* b1  = (const float*)d_in[4];
  const float* W2  = (const float*)d_in[5];
  const float* b2  = (const float*)d_in[6];
  const float* W3  = (const float*)d_in[7];
  const float* b3  = (const float*)d_in[8];
  const float* g1  = (const float*)d_in[9];
  const float* bt1 = (const float*)d_in[10];
  const float* g2  = (const float*)d_in[11];
  const float* bt2 = (const float*)d_in[12];
  const float* Wf  = (const float*)d_in[13];
  const float* bfb = (const float*)d_in[14];
  float* out = (float*)d_out;

  float* B0 = (float*)d_ws;
  float* B1 = B0 + NELEMS;
  float* B2 = B1 + NELEMS;
  float* B3 = B2 + NELEMS;
  float* sums = B3 + NELEMS;               // 512 floats: [0..255]=layer1, [256..511]=layer2
  int2* edges = (int2*)(sums + 512);       // N_EDGES int2 (8B-aligned)
  int* cursor = (int*)(edges + N_EDGES);   // N_NODES
  int* row_ptr = cursor + N_NODES;         // N_NODES+1
  int* bsum = row_ptr + N_NODES + 1;       // 512
  float* partials = (float*)(bsum + 512);  // 2048*256 floats (2MB)
  float* sums1 = sums;
  float* sums2 = sums + 256;

  // JAX partitionable split of key(42)=(0,42): k_i = threefry(key, (0,i)) full pair
  uint32_t k1_0, k1_1, k2_0, k2_1;
  threefry2x32(0u, 42u, 0u, 0u, k1_0, k1_1);
  threefry2x32(0u, 42u, 0u, 1u, k2_0, k2_1);

  const int GEMM_GRID = (N_NODES + 63) / 64;       // 1563 (64 rows/block)
  const int EDGE_GRID = (N_EDGES + 255) / 256;     // 2344
  const int NODE_GRID = (N_NODES + 255) / 256;     // 391
  const int AGG_GRID  = N_NODES / 4;               // 25000 (1 node/wave, 4 waves/block)
  const int STAT_GRID = 2048;
  const int RED_GRID  = 16;
  const int FINAL_GRID = N_NODES / 16;             // 6250

  // ---- CSR build (reused by all 3 layers)
  hipMemsetAsync(cursor, 0, N_NODES * sizeof(int), stream);
  hipMemsetAsync(sums, 0, 512 * sizeof(float), stream);
  csr_count<<<EDGE_GRID, 256, 0, stream>>>(ei, cursor);
  scan_blocks<<<NODE_GRID, 256, 0, stream>>>(cursor, bsum);
  scan_bsum<<<1, 512, 0, stream>>>(bsum, NODE_GRID);
  add_offsets<<<NODE_GRID, 256, 0, stream>>>(cursor, bsum, row_ptr);
  csr_fill<<<EDGE_GRID, 256, 0, stream>>>(ei, ew, cursor, edges);

  // ---- layer 1: P1 = x@W1 (MFMA bf16) ; AGG1 = gather(P1)+b1 ; stats1
  gemm_mfma<<<GEMM_GRID, 256, 0, stream>>>(x, W1, B0);
  gather_agg<<<AGG_GRID, 256, 0, stream>>>(B0, row_ptr, edges, b1, B1);
  bn_stats<<<STAT_GRID, 256, 0, stream>>>(B1, partials);
  reduce_partials<<<RED_GRID, 256, 0, stream>>>(partials, sums1, STAT_GRID);
  // ---- layer 2: fused BN1+ReLU (-> X1=B2) + dropout(k1) + MFMA GEMM W2 -> P2=B0
  gemm_mfma_fused<<<GEMM_GRID, 256, 0, stream>>>(B1, sums1, g1, bt1, W2, B2, B0, k1_0, k1_1);
  gather_agg<<<AGG_GRID, 256, 0, stream>>>(B0, row_ptr, edges, b2, B1);
  bn_stats<<<STAT_GRID, 256, 0, stream>>>(B1, partials);
  reduce_partials<<<RED_GRID, 256, 0, stream>>>(partials, sums2, STAT_GRID);
  // ---- layer 3: fused BN2+ReLU (-> X2=B3) + dropout(k2) + MFMA GEMM W3 -> P3=B0
  gemm_mfma_fused<<<GEMM_GRID, 256, 0, stream>>>(B1, sums2, g2, bt2, W3, B3, B0, k2_0, k2_1);
  gather_agg<<<AGG_GRID, 256, 0, stream>>>(B0, row_ptr, edges, b3, B1);
  // ---- JK max + final linear + log_softmax
  jk_final<<<FINAL_GRID, 256, 0, stream>>>(B2, B3, B1, Wf, bfb, out);
}

// Round 13
// 483.539 us; speedup vs baseline: 1.6959x; 1.0744x over previous
//
#include <hip/hip_runtime.h>
#include <stdint.h>

#define N_NODES 100000
#define N_EDGES 600000
#define HID 128
#define OUT_C 64
#define NELEMS 12800000      // 100000*128
#define BN_EPS 1e-5f
#define LP 136               // LDS row pitch in bf16 elems

typedef short bf16x8 __attribute__((ext_vector_type(8)));
typedef float f32x4 __attribute__((ext_vector_type(4)));

__device__ __forceinline__ unsigned short f2bf(float f) {   // RNE float->bf16
  uint32_t u = __float_as_uint(f);
  uint32_t r = u + 0x7FFFu + ((u >> 16) & 1u);
  return (unsigned short)(r >> 16);
}

// ---------------- threefry2x32 (matches JAX) ----------------
__device__ __host__ __forceinline__ void threefry2x32(uint32_t k0, uint32_t k1,
                                                      uint32_t x0, uint32_t x1,
                                                      uint32_t& o0, uint32_t& o1) {
  uint32_t ks0 = k0, ks1 = k1, ks2 = k0 ^ k1 ^ 0x1BD11BDAu;
  x0 += ks0; x1 += ks1;
#define TFR(r) { x0 += x1; x1 = (x1 << (r)) | (x1 >> (32 - (r))); x1 ^= x0; }
  TFR(13) TFR(15) TFR(26) TFR(6)
  x0 += ks1; x1 += ks2 + 1u;
  TFR(17) TFR(29) TFR(16) TFR(24)
  x0 += ks2; x1 += ks0 + 2u;
  TFR(13) TFR(15) TFR(26) TFR(6)
  x0 += ks0; x1 += ks1 + 3u;
  TFR(17) TFR(29) TFR(16) TFR(24)
  x0 += ks1; x1 += ks2 + 4u;
  TFR(13) TFR(15) TFR(26) TFR(6)
  x0 += ks2; x1 += ks0 + 5u;
#undef TFR
  o0 = x0; o1 = x1;
}

__device__ __forceinline__ uint32_t jax_bits32(uint32_t k0, uint32_t k1, uint32_t i) {
  uint32_t b0, b1;
  threefry2x32(k0, k1, 0u, i, b0, b1);
  return b0 ^ b1;
}

// ---------------- MFMA GEMM core pieces (bf16 in, bf16 OUT) ----------------
// Block: 256 thr = 4 waves; 64 rows; wave wv -> rows [wv*16, wv*16+16).
// A frag: lane holds A[m=lane&15][ks*32 + (lane>>4)*8 + 0..7]
// B frag: lane holds W[ks*32 + (lane>>4)*8 + 0..7][n*16 + (lane&15)]  (from Wt[c][k])
// C/D:    col = n*16 + (lane&15), row = (lane>>4)*4 + reg

__device__ __forceinline__ void stage_Wt(const float* __restrict__ W,
                                         unsigned short* Wt, int tid) {
#pragma unroll
  for (int i = 0; i < 16; ++i) {            // 4096 float4 = 128 k x 32 cq
    int f4 = tid + i * 256;
    int k = f4 >> 5;
    int cq = f4 & 31;
    float4 w = *(const float4*)(W + k * 128 + cq * 4);
    Wt[(cq * 4 + 0) * LP + k] = f2bf(w.x);
    Wt[(cq * 4 + 1) * LP + k] = f2bf(w.y);
    Wt[(cq * 4 + 2) * LP + k] = f2bf(w.z);
    Wt[(cq * 4 + 3) * LP + k] = f2bf(w.w);
  }
}

__device__ __forceinline__ void mfma_compute_store(const unsigned short* At,
                                                   const unsigned short* Wt,
                                                   unsigned short* __restrict__ O,
                                                   int rbase, int tid) {
  const int lane = tid & 63;
  const int wv = tid >> 6;
  const int m = lane & 15;
  const int kg = lane >> 4;
  f32x4 acc0 = {0,0,0,0}, acc1 = {0,0,0,0}, acc2 = {0,0,0,0}, acc3 = {0,0,0,0};
  f32x4 acc4 = {0,0,0,0}, acc5 = {0,0,0,0}, acc6 = {0,0,0,0}, acc7 = {0,0,0,0};
  const unsigned short* Arow = At + (wv * 16 + m) * LP;
#pragma unroll
  for (int ks = 0; ks < 4; ++ks) {
    bf16x8 af = *(const bf16x8*)(Arow + ks * 32 + kg * 8);
#define MF(n, accn) { bf16x8 bfr = *(const bf16x8*)(Wt + (n * 16 + m) * LP + ks * 32 + kg * 8); \
    accn = __builtin_amdgcn_mfma_f32_16x16x32_bf16(af, bfr, accn, 0, 0, 0); }
    MF(0, acc0) MF(1, acc1) MF(2, acc2) MF(3, acc3)
    MF(4, acc4) MF(5, acc5) MF(6, acc6) MF(7, acc7)
#undef MF
  }
#define ST(n, accn) {                                                       \
  _Pragma("unroll")                                                         \
  for (int j = 0; j < 4; ++j) {                                             \
    int grow = rbase + wv * 16 + kg * 4 + j;                                \
    if (grow < N_NODES) O[(size_t)grow * 128 + n * 16 + m] = f2bf(accn[j]); \
  } }
  ST(0, acc0) ST(1, acc1) ST(2, acc2) ST(3, acc3)
  ST(4, acc4) ST(5, acc5) ST(6, acc6) ST(7, acc7)
#undef ST
}

// plain (layer 1): O = bf16(A) @ bf16(W), O stored bf16
__global__ __launch_bounds__(256) void gemm_mfma(const float* __restrict__ A,
                                                 const float* __restrict__ W,
                                                 unsigned short* __restrict__ O) {
  __shared__ __align__(16) unsigned short Wt[128 * LP];
  __shared__ __align__(16) unsigned short At[64 * LP];
  const int tid = threadIdx.x;
  const int rbase = blockIdx.x * 64;
  stage_Wt(W, Wt, tid);
#pragma unroll
  for (int i = 0; i < 8; ++i) {             // 2048 float4 = 64 r x 32 cq
    int f4 = tid + i * 256;
    int r = f4 >> 5;
    int cq = f4 & 31;
    int grow = rbase + r;
    if (grow >= N_NODES) grow = N_NODES - 1;
    float4 a = *(const float4*)(A + (size_t)grow * 128 + cq * 4);
    uint32_t p0 = (uint32_t)f2bf(a.x) | ((uint32_t)f2bf(a.y) << 16);
    uint32_t p1 = (uint32_t)f2bf(a.z) | ((uint32_t)f2bf(a.w) << 16);
    *(uint2*)(At + r * LP + cq * 4) = make_uint2(p0, p1);
  }
  __syncthreads();
  mfma_compute_store(At, Wt, O, rbase, tid);
}

// fused (layers 2,3): BN+ReLU -> X (fp32), dropout -> bf16 A operand; O = A@W (bf16 out)
__global__ __launch_bounds__(256) void gemm_mfma_fused(const float* __restrict__ AGG,
                                                       const float* __restrict__ sums,
                                                       const float* __restrict__ g,
                                                       const float* __restrict__ bt,
                                                       const float* __restrict__ W,
                                                       float* __restrict__ X,
                                                       unsigned short* __restrict__ O,
                                                       uint32_t k0, uint32_t k1) {
  __shared__ __align__(16) unsigned short Wt[128 * LP];
  __shared__ __align__(16) unsigned short At[64 * LP];
  const int tid = threadIdx.x;
  const int rbase = blockIdx.x * 64;
  stage_Wt(W, Wt, tid);
#pragma unroll
  for (int i = 0; i < 8; ++i) {
    int f4 = tid + i * 256;
    int r = f4 >> 5;
    int cq = f4 & 31;
    int grow = rbase + r;
    bool valid = grow < N_NODES;
    int growc = valid ? grow : N_NODES - 1;
    float4 a = *(const float4*)(AGG + (size_t)growc * 128 + cq * 4);
    float y[4];
    unsigned short hd[4];
#pragma unroll
    for (int jj = 0; jj < 4; ++jj) {
      int c = cq * 4 + jj;
      float mu = sums[c] * (1.0f / N_NODES);
      float var = fmaxf(sums[128 + c] * (1.0f / N_NODES) - mu * mu, 0.f);
      float inv = rsqrtf(var + BN_EPS);
      float av = ((const float*)&a)[jj];
      float yv = fmaxf(g[c] * (av - mu) * inv + bt[c], 0.f);
      uint32_t bits = jax_bits32(k0, k1, (uint32_t)(growc * 128 + c));
      y[jj] = yv;
      hd[jj] = f2bf((bits & 0x80000000u) ? 0.f : 2.f * yv);
    }
    if (valid) *(float4*)(X + (size_t)grow * 128 + cq * 4) = *(float4*)y;
    uint32_t p0 = (uint32_t)hd[0] | ((uint32_t)hd[1] << 16);
    uint32_t p1 = (uint32_t)hd[2] | ((uint32_t)hd[3] << 16);
    *(uint2*)(At + r * LP + cq * 4) = make_uint2(p0, p1);
  }
  __syncthreads();
  mfma_compute_store(At, Wt, O, rbase, tid);
}

// ---------------- CSR build ----------------
__global__ __launch_bounds__(256) void csr_count(const int* __restrict__ ei,
                                                 int* __restrict__ cnt) {
  int e = blockIdx.x * 256 + threadIdx.x;
  if (e < N_EDGES) atomicAdd(&cnt[ei[e + N_EDGES]], 1);
}

__global__ __launch_bounds__(256) void scan_blocks(int* __restrict__ cnt,
                                                   int* __restrict__ bsum) {
  __shared__ int tmp[256];
  int tid = threadIdx.x;
  int i = blockIdx.x * 256 + tid;
  int v = (i < N_NODES) ? cnt[i] : 0;
  tmp[tid] = v;
  __syncthreads();
  for (int off = 1; off < 256; off <<= 1) {
    int t = (tid >= off) ? tmp[tid - off] : 0;
    __syncthreads();
    if (tid >= off) tmp[tid] += t;
    __syncthreads();
  }
  if (i < N_NODES) cnt[i] = tmp[tid] - v;
  if (tid == 255) bsum[blockIdx.x] = tmp[255];
}

__global__ __launch_bounds__(512) void scan_bsum(int* __restrict__ bsum, int nb) {
  __shared__ int tmp[512];
  int tid = threadIdx.x;
  int v = (tid < nb) ? bsum[tid] : 0;
  tmp[tid] = v;
  __syncthreads();
  for (int off = 1; off < 512; off <<= 1) {
    int t = (tid >= off) ? tmp[tid - off] : 0;
    __syncthreads();
    if (tid >= off) tmp[tid] += t;
    __syncthreads();
  }
  if (tid < nb) bsum[tid] = tmp[tid] - v;
}

__global__ __launch_bounds__(256) void add_offsets(int* __restrict__ cnt,
                                                   const int* __restrict__ bsum,
                                                   int* __restrict__ row_ptr) {
  int i = blockIdx.x * 256 + threadIdx.x;
  if (i < N_NODES) {
    int r = cnt[i] + bsum[blockIdx.x];
    row_ptr[i] = r;
    cnt[i] = r;
  }
  if (i == 0) row_ptr[N_NODES] = N_EDGES;
}

__global__ __launch_bounds__(256) void csr_fill(const int* __restrict__ ei,
                                                const float* __restrict__ ew,
                                                int* __restrict__ cursor,
                                                int2* __restrict__ edges) {
  int e = blockIdx.x * 256 + threadIdx.x;
  if (e < N_EDGES) {
    int d = ei[e + N_EDGES];
    int p = atomicAdd(&cursor[d], 1);
    edges[p] = make_int2(ei[e], __float_as_int(ew[e]));
  }
}

// ---------------- gather aggregation: AGG[n] = b + sum_{e->n} w_e * bf16row(H[src_e])
// H is bf16 [N][128]; lane loads one uint = 2 channels; fp32 accumulate.
__global__ __launch_bounds__(256) void gather_agg(const unsigned int* __restrict__ Hb,
                                                  const int* __restrict__ row_ptr,
                                                  const int2* __restrict__ edges,
                                                  const float* __restrict__ bias,
                                                  float* __restrict__ AGG) {
  const int node = blockIdx.x * 4 + (threadIdx.x >> 6);
  const int lane = threadIdx.x & 63;
  float2 acc = *(const float2*)(bias + lane * 2);
  const int beg = row_ptr[node];
  const int end = row_ptr[node + 1];
  int j = beg;
  for (; j + 3 < end; j += 4) {
    int2 e0 = edges[j + 0];
    int2 e1 = edges[j + 1];
    int2 e2 = edges[j + 2];
    int2 e3 = edges[j + 3];
    uint32_t u0 = Hb[(size_t)e0.x * 64 + lane];
    uint32_t u1 = Hb[(size_t)e1.x * 64 + lane];
    uint32_t u2 = Hb[(size_t)e2.x * 64 + lane];
    uint32_t u3 = Hb[(size_t)e3.x * 64 + lane];
    float w0 = __int_as_float(e0.y), w1 = __int_as_float(e1.y);
    float w2 = __int_as_float(e2.y), w3 = __int_as_float(e3.y);
    acc.x += w0 * __uint_as_float(u0 << 16) + w1 * __uint_as_float(u1 << 16)
           + w2 * __uint_as_float(u2 << 16) + w3 * __uint_as_float(u3 << 16);
    acc.y += w0 * __uint_as_float(u0 & 0xFFFF0000u) + w1 * __uint_as_float(u1 & 0xFFFF0000u)
           + w2 * __uint_as_float(u2 & 0xFFFF0000u) + w3 * __uint_as_float(u3 & 0xFFFF0000u);
  }
  for (; j < end; ++j) {
    int2 e = edges[j];
    uint32_t u = Hb[(size_t)e.x * 64 + lane];
    float w = __int_as_float(e.y);
    acc.x += w * __uint_as_float(u << 16);
    acc.y += w * __uint_as_float(u & 0xFFFF0000u);
  }
  *(float2*)(AGG + (size_t)node * 128 + lane * 2) = acc;
}

// ---------------- BN stats: per-channel sum & sumsq -> per-block partials
__global__ __launch_bounds__(256) void bn_stats(const float* __restrict__ H,
                                                float* __restrict__ partials) {
  const int c4 = (threadIdx.x & 31) * 4;
  const int rg = threadIdx.x >> 5;              // 0..7
  float4 s = make_float4(0.f, 0.f, 0.f, 0.f);
  float4 q = make_float4(0.f, 0.f, 0.f, 0.f);
  for (int row = blockIdx.x * 8 + rg; row < N_NODES; row += gridDim.x * 8) {
    float4 v = *(const float4*)(H + (size_t)row * 128 + c4);
    s.x += v.x; s.y += v.y; s.z += v.z; s.w += v.w;
    q.x += v.x * v.x; q.y += v.y * v.y; q.z += v.z * v.z; q.w += v.w * v.w;
  }
  __shared__ float ls[8][256];
  *(float4*)&ls[rg][c4] = s;
  *(float4*)&ls[rg][128 + c4] = q;
  __syncthreads();
  float t = 0.f;
#pragma unroll
  for (int g = 0; g < 8; ++g) t += ls[g][threadIdx.x];
  partials[blockIdx.x * 256 + threadIdx.x] = t;
}

__global__ __launch_bounds__(256) void reduce_partials(const float* __restrict__ partials,
                                                       float* __restrict__ sums, int nblk) {
  float s = 0.f;
  for (int b = blockIdx.x; b < nblk; b += gridDim.x)
    s += partials[b * 256 + threadIdx.x];
  unsafeAtomicAdd(&sums[threadIdx.x], s);
}

// ---------------- jk = max(x1,x2,x3); OUT = log_softmax(jk @ Wf + bf)
// ROUND-3 KNOWN-GOOD (69us) -- do not touch.
__global__ __launch_bounds__(256) void jk_final(const float* __restrict__ X1,
                                                const float* __restrict__ X2,
                                                const float* __restrict__ X3,
                                                const float* __restrict__ Wf,
                                                const float* __restrict__ bf,
                                                float* __restrict__ OUT) {
  __shared__ __align__(16) float Wl[128 * 64];
  __shared__ __align__(16) float Jl[16][128];
  int tid = threadIdx.x;
  int lane = tid & 63;
  int wv = tid >> 6;
  int rbase = blockIdx.x * 16;
  {
    const float4* ws = (const float4*)Wf;
    float4* wd = (float4*)Wl;
#pragma unroll
    for (int i = 0; i < 8; ++i) wd[tid + i * 256] = ws[tid + i * 256];
  }
#pragma unroll
  for (int i = 0; i < 2; ++i) {
    int f4 = tid + i * 256;
    int row = f4 >> 5;
    int q = f4 & 31;
    size_t off = (size_t)(rbase + row) * 128 + q * 4;
    float4 a = *(const float4*)(X1 + off);
    float4 b = *(const float4*)(X2 + off);
    float4 c = *(const float4*)(X3 + off);
    float4 m;
    m.x = fmaxf(fmaxf(a.x, b.x), c.x);
    m.y = fmaxf(fmaxf(a.y, b.y), c.y);
    m.z = fmaxf(fmaxf(a.z, b.z), c.z);
    m.w = fmaxf(fmaxf(a.w, b.w), c.w);
    *(float4*)&Jl[row][q * 4] = m;
  }
  __syncthreads();
  float acc[4];
  float bv = bf[lane];
#pragma unroll
  for (int j = 0; j < 4; ++j) acc[j] = bv;
#pragma unroll 4
  for (int k = 0; k < 128; k += 4) {
    float4 j0 = *(const float4*)&Jl[wv][k];
    float4 j1 = *(const float4*)&Jl[wv + 4][k];
    float4 j2 = *(const float4*)&Jl[wv + 8][k];
    float4 j3 = *(const float4*)&Jl[wv + 12][k];
#pragma unroll
    for (int kk = 0; kk < 4; ++kk) {
      float w = Wl[(k + kk) * 64 + lane];
      acc[0] += ((const float*)&j0)[kk] * w;
      acc[1] += ((const float*)&j1)[kk] * w;
      acc[2] += ((const float*)&j2)[kk] * w;
      acc[3] += ((const float*)&j3)[kk] * w;
    }
  }
#pragma unroll
  for (int j = 0; j < 4; ++j) {
    float v = acc[j];
    float m = v;
#pragma unroll
    for (int s = 32; s > 0; s >>= 1) m = fmaxf(m, __shfl_xor(m, s));
    float e = expf(v - m);
    float sum = e;
#pragma unroll
    for (int s = 32; s > 0; s >>= 1) sum += __shfl_xor(sum, s);
    OUT[(size_t)(rbase + wv + 4 * j) * 64 + lane] = v - m - logf(sum);
  }
}

extern "C" void kernel_launch(void* const* d_in, const int* in_sizes, int n_in,
                              void* d_out, int out_size, void* d_ws, size_t ws_size,
                              hipStream_t stream) {
  const float* x   = (const float*)d_in[0];
  const int*   ei  = (const int*)d_in[1];
  const float* ew  = (const float*)d_in[2];
  const float* W1  = (const float*)d_in[3];
  const float* b1  = (const float*)d_in[4];
  const float* W2  = (const float*)d_in[5];
  const float* b2  = (const float*)d_in[6];
  const float* W3  = (const float*)d_in[7];
  const float* b3  = (const float*)d_in[8];
  const float* g1  = (const float*)d_in[9];
  const float* bt1 = (const float*)d_in[10];
  const float* g2  = (const float*)d_in[11];
  const float* bt2 = (const float*)d_in[12];
  const float* Wf  = (const float*)d_in[13];
  const float* bfb = (const float*)d_in[14];
  float* out = (float*)d_out;

  float* B0 = (float*)d_ws;                // P buffer, used as bf16 (ushort) [NELEMS]
  float* B1 = B0 + NELEMS;                 // AGG fp32
  float* B2 = B1 + NELEMS;                 // X1 fp32
  float* B3 = B2 + NELEMS;                 // X2 fp32
  float* sums = B3 + NELEMS;               // 512 floats
  int2* edges = (int2*)(sums + 512);       // N_EDGES int2
  int* cursor = (int*)(edges + N_EDGES);   // N_NODES
  int* row_ptr = cursor + N_NODES;         // N_NODES+1
  int* bsum = row_ptr + N_NODES + 1;       // 512
  float* partials = (float*)(bsum + 512);  // 2048*256 floats (2MB)
  float* sums1 = sums;
  float* sums2 = sums + 256;
  unsigned short* P = (unsigned short*)B0;
  unsigned int* Pu = (unsigned int*)B0;

  // JAX partitionable split of key(42)=(0,42): k_i = threefry(key, (0,i)) full pair
  uint32_t k1_0, k1_1, k2_0, k2_1;
  threefry2x32(0u, 42u, 0u, 0u, k1_0, k1_1);
  threefry2x32(0u, 42u, 0u, 1u, k2_0, k2_1);

  const int GEMM_GRID = (N_NODES + 63) / 64;       // 1563
  const int EDGE_GRID = (N_EDGES + 255) / 256;     // 2344
  const int NODE_GRID = (N_NODES + 255) / 256;     // 391
  const int AGG_GRID  = N_NODES / 4;               // 25000
  const int STAT_GRID = 2048;
  const int RED_GRID  = 16;
  const int FINAL_GRID = N_NODES / 16;             // 6250

  // ---- CSR build (reused by all 3 layers)
  hipMemsetAsync(cursor, 0, N_NODES * sizeof(int), stream);
  hipMemsetAsync(sums, 0, 512 * sizeof(float), stream);
  csr_count<<<EDGE_GRID, 256, 0, stream>>>(ei, cursor);
  scan_blocks<<<NODE_GRID, 256, 0, stream>>>(cursor, bsum);
  scan_bsum<<<1, 512, 0, stream>>>(bsum, NODE_GRID);
  add_offsets<<<NODE_GRID, 256, 0, stream>>>(cursor, bsum, row_ptr);
  csr_fill<<<EDGE_GRID, 256, 0, stream>>>(ei, ew, cursor, edges);

  // ---- layer 1: P = bf16(x@W1) ; AGG1 = gather(P)+b1 ; stats1
  gemm_mfma<<<GEMM_GRID, 256, 0, stream>>>(x, W1, P);
  gather_agg<<<AGG_GRID, 256, 0, stream>>>(Pu, row_ptr, edges, b1, B1);
  bn_stats<<<STAT_GRID, 256, 0, stream>>>(B1, partials);
  reduce_partials<<<RED_GRID, 256, 0, stream>>>(partials, sums1, STAT_GRID);
  // ---- layer 2: fused BN1+ReLU (-> X1=B2) + dropout(k1) + MFMA GEMM W2 -> P
  gemm_mfma_fused<<<GEMM_GRID, 256, 0, stream>>>(B1, sums1, g1, bt1, W2, B2, P, k1_0, k1_1);
  gather_agg<<<AGG_GRID, 256, 0, stream>>>(Pu, row_ptr, edges, b2, B1);
  bn_stats<<<STAT_GRID, 256, 0, stream>>>(B1, partials);
  reduce_partials<<<RED_GRID, 256, 0, stream>>>(partials, sums2, STAT_GRID);
  // ---- layer 3: fused BN2+ReLU (-> X2=B3) + dropout(k2) + MFMA GEMM W3 -> P
  gemm_mfma_fused<<<GEMM_GRID, 256, 0, stream>>>(B1, sums2, g2, bt2, W3, B3, P, k2_0, k2_1);
  gather_agg<<<AGG_GRID, 256, 0, stream>>>(Pu, row_ptr, edges, b3, B1);
  // ---- JK max + final linear + log_softmax
  jk_final<<<FINAL_GRID, 256, 0, stream>>>(B2, B3, B1, Wf, bfb, out);
}

// Round 14
// 446.657 us; speedup vs baseline: 1.8360x; 1.0826x over previous
//
#include <hip/hip_runtime.h>
#include <stdint.h>

#define N_NODES 100000
#define N_EDGES 600000
#define HID 128
#define OUT_C 64
#define NELEMS 12800000      // 100000*128
#define BN_EPS 1e-5f
#define LP 136               // LDS row pitch in bf16 elems

typedef short bf16x8 __attribute__((ext_vector_type(8)));
typedef float f32x4 __attribute__((ext_vector_type(4)));

__device__ __forceinline__ unsigned short f2bf(float f) {   // RNE float->bf16
  uint32_t u = __float_as_uint(f);
  uint32_t r = u + 0x7FFFu + ((u >> 16) & 1u);
  return (unsigned short)(r >> 16);
}
__device__ __forceinline__ float bf_lo(uint32_t u) { return __uint_as_float(u << 16); }
__device__ __forceinline__ float bf_hi(uint32_t u) { return __uint_as_float(u & 0xFFFF0000u); }

// ---------------- threefry2x32 (matches JAX) ----------------
__device__ __host__ __forceinline__ void threefry2x32(uint32_t k0, uint32_t k1,
                                                      uint32_t x0, uint32_t x1,
                                                      uint32_t& o0, uint32_t& o1) {
  uint32_t ks0 = k0, ks1 = k1, ks2 = k0 ^ k1 ^ 0x1BD11BDAu;
  x0 += ks0; x1 += ks1;
#define TFR(r) { x0 += x1; x1 = (x1 << (r)) | (x1 >> (32 - (r))); x1 ^= x0; }
  TFR(13) TFR(15) TFR(26) TFR(6)
  x0 += ks1; x1 += ks2 + 1u;
  TFR(17) TFR(29) TFR(16) TFR(24)
  x0 += ks2; x1 += ks0 + 2u;
  TFR(13) TFR(15) TFR(26) TFR(6)
  x0 += ks0; x1 += ks1 + 3u;
  TFR(17) TFR(29) TFR(16) TFR(24)
  x0 += ks1; x1 += ks2 + 4u;
  TFR(13) TFR(15) TFR(26) TFR(6)
  x0 += ks2; x1 += ks0 + 5u;
#undef TFR
  o0 = x0; o1 = x1;
}

__device__ __forceinline__ uint32_t jax_bits32(uint32_t k0, uint32_t k1, uint32_t i) {
  uint32_t b0, b1;
  threefry2x32(k0, k1, 0u, i, b0, b1);
  return b0 ^ b1;
}

// ---------------- MFMA GEMM core pieces (bf16 in, bf16 OUT) ----------------
__device__ __forceinline__ void stage_Wt(const float* __restrict__ W,
                                         unsigned short* Wt, int tid) {
#pragma unroll
  for (int i = 0; i < 16; ++i) {            // 4096 float4 = 128 k x 32 cq
    int f4 = tid + i * 256;
    int k = f4 >> 5;
    int cq = f4 & 31;
    float4 w = *(const float4*)(W + k * 128 + cq * 4);
    Wt[(cq * 4 + 0) * LP + k] = f2bf(w.x);
    Wt[(cq * 4 + 1) * LP + k] = f2bf(w.y);
    Wt[(cq * 4 + 2) * LP + k] = f2bf(w.z);
    Wt[(cq * 4 + 3) * LP + k] = f2bf(w.w);
  }
}

__device__ __forceinline__ void mfma_compute_store(const unsigned short* At,
                                                   const unsigned short* Wt,
                                                   unsigned short* __restrict__ O,
                                                   int rbase, int tid) {
  const int lane = tid & 63;
  const int wv = tid >> 6;
  const int m = lane & 15;
  const int kg = lane >> 4;
  f32x4 acc0 = {0,0,0,0}, acc1 = {0,0,0,0}, acc2 = {0,0,0,0}, acc3 = {0,0,0,0};
  f32x4 acc4 = {0,0,0,0}, acc5 = {0,0,0,0}, acc6 = {0,0,0,0}, acc7 = {0,0,0,0};
  const unsigned short* Arow = At + (wv * 16 + m) * LP;
#pragma unroll
  for (int ks = 0; ks < 4; ++ks) {
    bf16x8 af = *(const bf16x8*)(Arow + ks * 32 + kg * 8);
#define MF(n, accn) { bf16x8 bfr = *(const bf16x8*)(Wt + (n * 16 + m) * LP + ks * 32 + kg * 8); \
    accn = __builtin_amdgcn_mfma_f32_16x16x32_bf16(af, bfr, accn, 0, 0, 0); }
    MF(0, acc0) MF(1, acc1) MF(2, acc2) MF(3, acc3)
    MF(4, acc4) MF(5, acc5) MF(6, acc6) MF(7, acc7)
#undef MF
  }
#define ST(n, accn) {                                                       \
  _Pragma("unroll")                                                         \
  for (int j = 0; j < 4; ++j) {                                             \
    int grow = rbase + wv * 16 + kg * 4 + j;                                \
    if (grow < N_NODES) O[(size_t)grow * 128 + n * 16 + m] = f2bf(accn[j]); \
  } }
  ST(0, acc0) ST(1, acc1) ST(2, acc2) ST(3, acc3)
  ST(4, acc4) ST(5, acc5) ST(6, acc6) ST(7, acc7)
#undef ST
}

// plain (layer 1): O = bf16(A) @ bf16(W), O stored bf16
__global__ __launch_bounds__(256) void gemm_mfma(const float* __restrict__ A,
                                                 const float* __restrict__ W,
                                                 unsigned short* __restrict__ O) {
  __shared__ __align__(16) unsigned short Wt[128 * LP];
  __shared__ __align__(16) unsigned short At[64 * LP];
  const int tid = threadIdx.x;
  const int rbase = blockIdx.x * 64;
  stage_Wt(W, Wt, tid);
#pragma unroll
  for (int i = 0; i < 8; ++i) {             // 2048 float4 = 64 r x 32 cq
    int f4 = tid + i * 256;
    int r = f4 >> 5;
    int cq = f4 & 31;
    int grow = rbase + r;
    if (grow >= N_NODES) grow = N_NODES - 1;
    float4 a = *(const float4*)(A + (size_t)grow * 128 + cq * 4);
    uint32_t p0 = (uint32_t)f2bf(a.x) | ((uint32_t)f2bf(a.y) << 16);
    uint32_t p1 = (uint32_t)f2bf(a.z) | ((uint32_t)f2bf(a.w) << 16);
    *(uint2*)(At + r * LP + cq * 4) = make_uint2(p0, p1);
  }
  __syncthreads();
  mfma_compute_store(At, Wt, O, rbase, tid);
}

// fused (layers 2,3): BN+ReLU -> X (bf16 packed), dropout -> bf16 A; O = A@W (bf16)
__global__ __launch_bounds__(256) void gemm_mfma_fused(const float* __restrict__ AGG,
                                                       const float* __restrict__ sums,
                                                       const float* __restrict__ g,
                                                       const float* __restrict__ bt,
                                                       const float* __restrict__ W,
                                                       unsigned int* __restrict__ Xb,
                                                       unsigned short* __restrict__ O,
                                                       uint32_t k0, uint32_t k1) {
  __shared__ __align__(16) unsigned short Wt[128 * LP];
  __shared__ __align__(16) unsigned short At[64 * LP];
  const int tid = threadIdx.x;
  const int rbase = blockIdx.x * 64;
  stage_Wt(W, Wt, tid);
#pragma unroll
  for (int i = 0; i < 8; ++i) {
    int f4 = tid + i * 256;
    int r = f4 >> 5;
    int cq = f4 & 31;
    int grow = rbase + r;
    bool valid = grow < N_NODES;
    int growc = valid ? grow : N_NODES - 1;
    float4 a = *(const float4*)(AGG + (size_t)growc * 128 + cq * 4);
    unsigned short yb[4], hd[4];
#pragma unroll
    for (int jj = 0; jj < 4; ++jj) {
      int c = cq * 4 + jj;
      float mu = sums[c] * (1.0f / N_NODES);
      float var = fmaxf(sums[128 + c] * (1.0f / N_NODES) - mu * mu, 0.f);
      float inv = rsqrtf(var + BN_EPS);
      float av = ((const float*)&a)[jj];
      float yv = fmaxf(g[c] * (av - mu) * inv + bt[c], 0.f);
      uint32_t bits = jax_bits32(k0, k1, (uint32_t)(growc * 128 + c));
      yb[jj] = f2bf(yv);
      hd[jj] = f2bf((bits & 0x80000000u) ? 0.f : 2.f * yv);
    }
    if (valid) {
      uint2 yp = make_uint2((uint32_t)yb[0] | ((uint32_t)yb[1] << 16),
                            (uint32_t)yb[2] | ((uint32_t)yb[3] << 16));
      *(uint2*)(Xb + (size_t)grow * 64 + cq * 2) = yp;
    }
    uint32_t p0 = (uint32_t)hd[0] | ((uint32_t)hd[1] << 16);
    uint32_t p1 = (uint32_t)hd[2] | ((uint32_t)hd[3] << 16);
    *(uint2*)(At + r * LP + cq * 4) = make_uint2(p0, p1);
  }
  __syncthreads();
  mfma_compute_store(At, Wt, O, rbase, tid);
}

// ---------------- CSR build ----------------
__global__ __launch_bounds__(256) void csr_count(const int* __restrict__ ei,
                                                 int* __restrict__ cnt) {
  int e = blockIdx.x * 256 + threadIdx.x;
  if (e < N_EDGES) atomicAdd(&cnt[ei[e + N_EDGES]], 1);
}

__global__ __launch_bounds__(256) void scan_blocks(int* __restrict__ cnt,
                                                   int* __restrict__ bsum) {
  __shared__ int tmp[256];
  int tid = threadIdx.x;
  int i = blockIdx.x * 256 + tid;
  int v = (i < N_NODES) ? cnt[i] : 0;
  tmp[tid] = v;
  __syncthreads();
  for (int off = 1; off < 256; off <<= 1) {
    int t = (tid >= off) ? tmp[tid - off] : 0;
    __syncthreads();
    if (tid >= off) tmp[tid] += t;
    __syncthreads();
  }
  if (i < N_NODES) cnt[i] = tmp[tid] - v;
  if (tid == 255) bsum[blockIdx.x] = tmp[255];
}

__global__ __launch_bounds__(512) void scan_bsum(int* __restrict__ bsum, int nb) {
  __shared__ int tmp[512];
  int tid = threadIdx.x;
  int v = (tid < nb) ? bsum[tid] : 0;
  tmp[tid] = v;
  __syncthreads();
  for (int off = 1; off < 512; off <<= 1) {
    int t = (tid >= off) ? tmp[tid - off] : 0;
    __syncthreads();
    if (tid >= off) tmp[tid] += t;
    __syncthreads();
  }
  if (tid < nb) bsum[tid] = tmp[tid] - v;
}

__global__ __launch_bounds__(256) void add_offsets(int* __restrict__ cnt,
                                                   const int* __restrict__ bsum,
                                                   int* __restrict__ row_ptr) {
  int i = blockIdx.x * 256 + threadIdx.x;
  if (i < N_NODES) {
    int r = cnt[i] + bsum[blockIdx.x];
    row_ptr[i] = r;
    cnt[i] = r;
  }
  if (i == 0) row_ptr[N_NODES] = N_EDGES;
}

__global__ __launch_bounds__(256) void csr_fill(const int* __restrict__ ei,
                                                const float* __restrict__ ew,
                                                int* __restrict__ cursor,
                                                int2* __restrict__ edges) {
  int e = blockIdx.x * 256 + threadIdx.x;
  if (e < N_EDGES) {
    int d = ei[e + N_EDGES];
    int p = atomicAdd(&cursor[d], 1);
    edges[p] = make_int2(ei[e], __float_as_int(ew[e]));
  }
}

// ---------------- gather aggregation: AGG[n] = b + sum_{e->n} w_e * bf16row(H[src_e])
__global__ __launch_bounds__(256) void gather_agg(const unsigned int* __restrict__ Hb,
                                                  const int* __restrict__ row_ptr,
                                                  const int2* __restrict__ edges,
                                                  const float* __restrict__ bias,
                                                  float* __restrict__ AGG) {
  const int node = blockIdx.x * 4 + (threadIdx.x >> 6);
  const int lane = threadIdx.x & 63;
  float2 acc = *(const float2*)(bias + lane * 2);
  const int beg = row_ptr[node];
  const int end = row_ptr[node + 1];
  int j = beg;
  for (; j + 3 < end; j += 4) {
    int2 e0 = edges[j + 0];
    int2 e1 = edges[j + 1];
    int2 e2 = edges[j + 2];
    int2 e3 = edges[j + 3];
    uint32_t u0 = Hb[(size_t)e0.x * 64 + lane];
    uint32_t u1 = Hb[(size_t)e1.x * 64 + lane];
    uint32_t u2 = Hb[(size_t)e2.x * 64 + lane];
    uint32_t u3 = Hb[(size_t)e3.x * 64 + lane];
    float w0 = __int_as_float(e0.y), w1 = __int_as_float(e1.y);
    float w2 = __int_as_float(e2.y), w3 = __int_as_float(e3.y);
    acc.x += w0 * bf_lo(u0) + w1 * bf_lo(u1) + w2 * bf_lo(u2) + w3 * bf_lo(u3);
    acc.y += w0 * bf_hi(u0) + w1 * bf_hi(u1) + w2 * bf_hi(u2) + w3 * bf_hi(u3);
  }
  for (; j < end; ++j) {
    int2 e = edges[j];
    uint32_t u = Hb[(size_t)e.x * 64 + lane];
    float w = __int_as_float(e.y);
    acc.x += w * bf_lo(u);
    acc.y += w * bf_hi(u);
  }
  *(float2*)(AGG + (size_t)node * 128 + lane * 2) = acc;
}

// ---------------- BN stats: per-channel sum & sumsq -> per-block partials
__global__ __launch_bounds__(256) void bn_stats(const float* __restrict__ H,
                                                float* __restrict__ partials) {
  const int c4 = (threadIdx.x & 31) * 4;
  const int rg = threadIdx.x >> 5;              // 0..7
  float4 s = make_float4(0.f, 0.f, 0.f, 0.f);
  float4 q = make_float4(0.f, 0.f, 0.f, 0.f);
  for (int row = blockIdx.x * 8 + rg; row < N_NODES; row += gridDim.x * 8) {
    float4 v = *(const float4*)(H + (size_t)row * 128 + c4);
    s.x += v.x; s.y += v.y; s.z += v.z; s.w += v.w;
    q.x += v.x * v.x; q.y += v.y * v.y; q.z += v.z * v.z; q.w += v.w * v.w;
  }
  __shared__ float ls[8][256];
  *(float4*)&ls[rg][c4] = s;
  *(float4*)&ls[rg][128 + c4] = q;
  __syncthreads();
  float t = 0.f;
#pragma unroll
  for (int g = 0; g < 8; ++g) t += ls[g][threadIdx.x];
  partials[blockIdx.x * 256 + threadIdx.x] = t;
}

__global__ __launch_bounds__(256) void reduce_partials(const float* __restrict__ partials,
                                                       float* __restrict__ sums, int nblk) {
  float s = 0.f;
  for (int b = blockIdx.x; b < nblk; b += gridDim.x)
    s += partials[b * 256 + threadIdx.x];
  unsafeAtomicAdd(&sums[threadIdx.x], s);
}

// ---------------- jk_final via MFMA: jk = max(bf16 X1, bf16 X2, fp32 X3);
// OUT = log_softmax(jk @ Wf + bf). 64 rows/block; A=jk bf16, B=Wf^T bf16 in LDS;
// 4 N-tiles x 4 K-steps per wave; bias in epilogue; 16-lane shuffle log_softmax.
__global__ __launch_bounds__(256) void jk_final_mfma(const unsigned int* __restrict__ X1b,
                                                     const unsigned int* __restrict__ X2b,
                                                     const float* __restrict__ X3,
                                                     const float* __restrict__ Wf,
                                                     const float* __restrict__ bf,
                                                     float* __restrict__ OUT) {
  __shared__ __align__(16) unsigned short Wt[64 * LP];   // Wt[col][k]
  __shared__ __align__(16) unsigned short At[64 * LP];   // jk rows bf16
  const int tid = threadIdx.x;
  const int rbase = blockIdx.x * 64;
  // stage Wf^T: Wf is [128 k][64 c]
#pragma unroll
  for (int i = 0; i < 8; ++i) {             // 2048 float4 = 128 k x 16 cq
    int f4 = tid + i * 256;
    int k = f4 >> 4;
    int cq = f4 & 15;
    float4 w = *(const float4*)(Wf + k * 64 + cq * 4);
    Wt[(cq * 4 + 0) * LP + k] = f2bf(w.x);
    Wt[(cq * 4 + 1) * LP + k] = f2bf(w.y);
    Wt[(cq * 4 + 2) * LP + k] = f2bf(w.z);
    Wt[(cq * 4 + 3) * LP + k] = f2bf(w.w);
  }
  // stage jk = max(x1,x2,x3) as bf16
#pragma unroll
  for (int i = 0; i < 8; ++i) {             // 2048 quads = 64 r x 32 cq
    int f4 = tid + i * 256;
    int r = f4 >> 5;
    int cq = f4 & 31;
    int grow = rbase + r;
    if (grow >= N_NODES) grow = N_NODES - 1;
    uint2 u1 = *(const uint2*)(X1b + (size_t)grow * 64 + cq * 2);
    uint2 u2 = *(const uint2*)(X2b + (size_t)grow * 64 + cq * 2);
    float4 x3 = *(const float4*)(X3 + (size_t)grow * 128 + cq * 4);
    float m0 = fmaxf(fmaxf(bf_lo(u1.x), bf_lo(u2.x)), x3.x);
    float m1 = fmaxf(fmaxf(bf_hi(u1.x), bf_hi(u2.x)), x3.y);
    float m2 = fmaxf(fmaxf(bf_lo(u1.y), bf_lo(u2.y)), x3.z);
    float m3 = fmaxf(fmaxf(bf_hi(u1.y), bf_hi(u2.y)), x3.w);
    uint32_t p0 = (uint32_t)f2bf(m0) | ((uint32_t)f2bf(m1) << 16);
    uint32_t p1 = (uint32_t)f2bf(m2) | ((uint32_t)f2bf(m3) << 16);
    *(uint2*)(At + r * LP + cq * 4) = make_uint2(p0, p1);
  }
  __syncthreads();
  const int lane = tid & 63;
  const int wv = tid >> 6;
  const int m = lane & 15;
  const int kg = lane >> 4;
  f32x4 acc0 = {0,0,0,0}, acc1 = {0,0,0,0}, acc2 = {0,0,0,0}, acc3 = {0,0,0,0};
  const unsigned short* Arow = At + (wv * 16 + m) * LP;
#pragma unroll
  for (int ks = 0; ks < 4; ++ks) {
    bf16x8 af = *(const bf16x8*)(Arow + ks * 32 + kg * 8);
#define MF(n, accn) { bf16x8 bfr = *(const bf16x8*)(Wt + (n * 16 + m) * LP + ks * 32 + kg * 8); \
    accn = __builtin_amdgcn_mfma_f32_16x16x32_bf16(af, bfr, accn, 0, 0, 0); }
    MF(0, acc0) MF(1, acc1) MF(2, acc2) MF(3, acc3)
#undef MF
  }
  float bf0 = bf[m], bf1 = bf[16 + m], bf2 = bf[32 + m], bf3 = bf[48 + m];
#pragma unroll
  for (int j = 0; j < 4; ++j) {
    int row = rbase + wv * 16 + kg * 4 + j;
    float v0 = acc0[j] + bf0;
    float v1 = acc1[j] + bf1;
    float v2 = acc2[j] + bf2;
    float v3 = acc3[j] + bf3;
    float M = fmaxf(fmaxf(v0, v1), fmaxf(v2, v3));
#pragma unroll
    for (int s = 1; s < 16; s <<= 1) M = fmaxf(M, __shfl_xor(M, s));
    float sum = expf(v0 - M) + expf(v1 - M) + expf(v2 - M) + expf(v3 - M);
#pragma unroll
    for (int s = 1; s < 16; s <<= 1) sum += __shfl_xor(sum, s);
    float ls = M + logf(sum);
    if (row < N_NODES) {
      float* o = OUT + (size_t)row * 64;
      o[m] = v0 - ls;
      o[16 + m] = v1 - ls;
      o[32 + m] = v2 - ls;
      o[48 + m] = v3 - ls;
    }
  }
}

extern "C" void kernel_launch(void* const* d_in, const int* in_sizes, int n_in,
                              void* d_out, int out_size, void* d_ws, size_t ws_size,
                              hipStream_t stream) {
  const float* x   = (const float*)d_in[0];
  const int*   ei  = (const int*)d_in[1];
  const float* ew  = (const float*)d_in[2];
  const float* W1  = (const float*)d_in[3];
  const float* b1  = (const float*)d_in[4];
  const float* W2  = (const float*)d_in[5];
  const float* b2  = (const float*)d_in[6];
  const float* W3  = (const float*)d_in[7];
  const float* b3  = (const float*)d_in[8];
  const float* g1  = (const float*)d_in[9];
  const float* bt1 = (const float*)d_in[10];
  const float* g2  = (const float*)d_in[11];
  const float* bt2 = (const float*)d_in[12];
  const float* Wf  = (const float*)d_in[13];
  const float* bfb = (const float*)d_in[14];
  float* out = (float*)d_out;

  float* B0 = (float*)d_ws;                // P buffer (bf16 ushort[NELEMS])
  float* B1 = B0 + NELEMS;                 // AGG fp32
  float* B2 = B1 + NELEMS;                 // X1 bf16 (uses half)
  float* B3 = B2 + NELEMS;                 // X2 bf16 (uses half)
  float* sums = B3 + NELEMS;               // 512 floats
  int2* edges = (int2*)(sums + 512);       // N_EDGES int2
  int* cursor = (int*)(edges + N_EDGES);   // N_NODES
  int* row_ptr = cursor + N_NODES;         // N_NODES+1
  int* bsum = row_ptr + N_NODES + 1;       // 512
  float* partials = (float*)(bsum + 512);  // 2048*256 floats (2MB)
  float* sums1 = sums;
  float* sums2 = sums + 256;
  unsigned short* P = (unsigned short*)B0;
  unsigned int* Pu = (unsigned int*)B0;
  unsigned int* X1b = (unsigned int*)B2;
  unsigned int* X2b = (unsigned int*)B3;

  // JAX partitionable split of key(42)=(0,42): k_i = threefry(key, (0,i)) full pair
  uint32_t k1_0, k1_1, k2_0, k2_1;
  threefry2x32(0u, 42u, 0u, 0u, k1_0, k1_1);
  threefry2x32(0u, 42u, 0u, 1u, k2_0, k2_1);

  const int GEMM_GRID = (N_NODES + 63) / 64;       // 1563
  const int EDGE_GRID = (N_EDGES + 255) / 256;     // 2344
  const int NODE_GRID = (N_NODES + 255) / 256;     // 391
  const int AGG_GRID  = N_NODES / 4;               // 25000
  const int STAT_GRID = 2048;
  const int RED_GRID  = 16;
  const int FINAL_GRID = (N_NODES + 63) / 64;      // 1563

  // ---- CSR build (reused by all 3 layers)
  hipMemsetAsync(cursor, 0, N_NODES * sizeof(int), stream);
  hipMemsetAsync(sums, 0, 512 * sizeof(float), stream);
  csr_count<<<EDGE_GRID, 256, 0, stream>>>(ei, cursor);
  scan_blocks<<<NODE_GRID, 256, 0, stream>>>(cursor, bsum);
  scan_bsum<<<1, 512, 0, stream>>>(bsum, NODE_GRID);
  add_offsets<<<NODE_GRID, 256, 0, stream>>>(cursor, bsum, row_ptr);
  csr_fill<<<EDGE_GRID, 256, 0, stream>>>(ei, ew, cursor, edges);

  // ---- layer 1: P = bf16(x@W1) ; AGG1 = gather(P)+b1 ; stats1
  gemm_mfma<<<GEMM_GRID, 256, 0, stream>>>(x, W1, P);
  gather_agg<<<AGG_GRID, 256, 0, stream>>>(Pu, row_ptr, edges, b1, B1);
  bn_stats<<<STAT_GRID, 256, 0, stream>>>(B1, partials);
  reduce_partials<<<RED_GRID, 256, 0, stream>>>(partials, sums1, STAT_GRID);
  // ---- layer 2: fused BN1+ReLU (-> X1 bf16) + dropout(k1) + MFMA GEMM W2 -> P
  gemm_mfma_fused<<<GEMM_GRID, 256, 0, stream>>>(B1, sums1, g1, bt1, W2, X1b, P, k1_0, k1_1);
  gather_agg<<<AGG_GRID, 256, 0, stream>>>(Pu, row_ptr, edges, b2, B1);
  bn_stats<<<STAT_GRID, 256, 0, stream>>>(B1, partials);
  reduce_partials<<<RED_GRID, 256, 0, stream>>>(partials, sums2, STAT_GRID);
  // ---- layer 3: fused BN2+ReLU (-> X2 bf16) + dropout(k2) + MFMA GEMM W3 -> P
  gemm_mfma_fused<<<GEMM_GRID, 256, 0, stream>>>(B1, sums2, g2, bt2, W3, X2b, P, k2_0, k2_1);
  gather_agg<<<AGG_GRID, 256, 0, stream>>>(Pu, row_ptr, edges, b3, B1);
  // ---- JK max + final linear + log_softmax (MFMA)
  jk_final_mfma<<<FINAL_GRID, 256, 0, stream>>>(X1b, X2b, B1, Wf, bfb, out);
}